// Round 1
// baseline (562.911 us; speedup 1.0000x reference)
//
#include <hip/hip_runtime.h>

#define NB 2
#define NN 8192
#define NM 32
#define ND 256
#define NH 8
#define NHD 32
#define NFF 1024
#define NROWS (NB*NN)   // 16384

typedef __attribute__((ext_vector_type(8))) short short8;
typedef __attribute__((ext_vector_type(4))) float floatx4;

__device__ __forceinline__ unsigned short f2bf(float f){
  unsigned u = __float_as_uint(f);
  u += 0x7fffu + ((u >> 16) & 1u);
  return (unsigned short)(u >> 16);
}
__device__ __forceinline__ float bf2f(unsigned short s){
  return __uint_as_float(((unsigned)s) << 16);
}

// ---------------- f32 -> bf16 convert ----------------
__global__ __launch_bounds__(256) void cvt_bf16(const float* __restrict__ in,
                                                unsigned short* __restrict__ out, int n4){
  int i = blockIdx.x * 256 + threadIdx.x;
  if (i >= n4) return;
  float4 v = ((const float4*)in)[i];
  ushort4 o;
  o.x = f2bf(v.x); o.y = f2bf(v.y); o.z = f2bf(v.z); o.w = f2bf(v.w);
  ((ushort4*)out)[i] = o;
}

// ---------------- GEMM: C = A[Mr x K](bf16) * W[Nc x K](bf16)^T + bias, epilogues ----
// EPI 0: (acc+bias)*scale -> f32 ; EPI 1: acc+bias -> f32 ; EPI 2: relu(acc+bias) -> bf16
template<int EPI>
__global__ __launch_bounds__(256) void gemm_bt(const unsigned short* __restrict__ A,
    const unsigned short* __restrict__ W, const float* __restrict__ bias,
    void* __restrict__ out, int Mr, int Nc, int K, float scale){
  __shared__ unsigned short As[128][40];   // +8 pad: 80B stride -> conflict-free b128
  __shared__ unsigned short Bs[128][40];
  const int tid = threadIdx.x;
  const int wid = tid >> 6, lane = tid & 63, ln = lane & 15, kh = lane >> 4;
  const int wr = (wid >> 1) * 64, wc = (wid & 1) * 64;
  const int row0 = blockIdx.x * 128, col0 = blockIdx.y * 128;
  const int lr = tid >> 2, lc = (tid & 3) * 8;
  floatx4 acc[4][4] = {};
  for (int k0 = 0; k0 < K; k0 += 32){
    __syncthreads();
    *(short8*)&As[lr][lc]    = *(const short8*)&A[(size_t)(row0+lr)*K + k0 + lc];
    *(short8*)&As[lr+64][lc] = *(const short8*)&A[(size_t)(row0+lr+64)*K + k0 + lc];
    *(short8*)&Bs[lr][lc]    = *(const short8*)&W[(size_t)(col0+lr)*K + k0 + lc];
    *(short8*)&Bs[lr+64][lc] = *(const short8*)&W[(size_t)(col0+lr+64)*K + k0 + lc];
    __syncthreads();
    short8 af[4], bf[4];
    #pragma unroll
    for (int t = 0; t < 4; ++t) af[t] = *(const short8*)&As[wr + t*16 + ln][kh*8];
    #pragma unroll
    for (int t = 0; t < 4; ++t) bf[t] = *(const short8*)&Bs[wc + t*16 + ln][kh*8];
    #pragma unroll
    for (int mt = 0; mt < 4; ++mt)
      #pragma unroll
      for (int nt = 0; nt < 4; ++nt)
        acc[mt][nt] = __builtin_amdgcn_mfma_f32_16x16x32_bf16(af[mt], bf[nt], acc[mt][nt], 0, 0, 0);
  }
  #pragma unroll
  for (int mt = 0; mt < 4; ++mt){
    #pragma unroll
    for (int nt = 0; nt < 4; ++nt){
      const int gc = col0 + wc + nt*16 + ln;
      const float bs = bias[gc];
      #pragma unroll
      for (int r = 0; r < 4; ++r){
        const int gr = row0 + wr + mt*16 + kh*4 + r;
        float v = acc[mt][nt][r] + bs;
        if (EPI == 0)      ((float*)out)[(size_t)gr*Nc + gc] = v * scale;
        else if (EPI == 1) ((float*)out)[(size_t)gr*Nc + gc] = v;
        else               ((unsigned short*)out)[(size_t)gr*Nc + gc] = f2bf(fmaxf(v, 0.f));
      }
    }
  }
}

// ---------------- fused neighbor attention: 2 nodes per WG ----------------
__global__ __launch_bounds__(256) void attn_kernel(
    const float* __restrict__ neigh, const int* __restrict__ mask,
    const unsigned short* __restrict__ Wk, const unsigned short* __restrict__ Wv,
    const float* __restrict__ bk, const float* __restrict__ bv,
    const float* __restrict__ Qw, unsigned short* __restrict__ att){
  __shared__ unsigned short Xs[64][264];   // 2 nodes x 32 m, bf16, padded
  __shared__ unsigned short KVs[64][264];  // K then V (reused)
  __shared__ float Qs[2][ND];
  __shared__ float Pw[2][NH][NM];
  __shared__ int ms[2][NM];
  const int tid = threadIdx.x;
  const int wid = tid >> 6, lane = tid & 63, ln = lane & 15, kh = lane >> 4;
  const size_t nid0 = (size_t)blockIdx.x * 2;

  { // stage X (f32 -> bf16), Q, mask
    const float4* src = (const float4*)(neigh + nid0 * (NM*ND));
    for (int i = tid; i < 64*64; i += 256){
      const int r = i >> 6, c = (i & 63) * 4;
      const float4 v = src[i];
      ushort4 o; o.x = f2bf(v.x); o.y = f2bf(v.y); o.z = f2bf(v.z); o.w = f2bf(v.w);
      *(ushort4*)&Xs[r][c] = o;
    }
    if (tid < 128) ((float4*)&Qs[0][0])[tid] = ((const float4*)(Qw + nid0*ND))[tid];
    if (tid < 64)  ms[tid>>5][tid&31] = mask[nid0*NM + tid];
  }
  __syncthreads();

  { // K = X * Wk^T + bk  -> KVs (bf16). wave owns 64 output cols; no barrier in k-loop
    floatx4 acc[4][4] = {};
    for (int kk = 0; kk < 8; ++kk){
      short8 af[4], bf[4];
      #pragma unroll
      for (int t = 0; t < 4; ++t) af[t] = *(const short8*)&Xs[t*16 + ln][kk*32 + kh*8];
      #pragma unroll
      for (int t = 0; t < 4; ++t) bf[t] = *(const short8*)&Wk[(size_t)(wid*64 + t*16 + ln)*ND + kk*32 + kh*8];
      #pragma unroll
      for (int mt = 0; mt < 4; ++mt)
        #pragma unroll
        for (int nt = 0; nt < 4; ++nt)
          acc[mt][nt] = __builtin_amdgcn_mfma_f32_16x16x32_bf16(af[mt], bf[nt], acc[mt][nt], 0, 0, 0);
    }
    #pragma unroll
    for (int mt = 0; mt < 4; ++mt)
      #pragma unroll
      for (int nt = 0; nt < 4; ++nt){
        const int col = wid*64 + nt*16 + ln;
        const float bb = bk[col];
        #pragma unroll
        for (int r = 0; r < 4; ++r)
          KVs[mt*16 + kh*4 + r][col] = f2bf(acc[mt][nt][r] + bb);
      }
  }
  __syncthreads();

  { // scores + softmax: thread = (h, m)
    const int h = tid >> 5, m = tid & 31;
    #pragma unroll
    for (int node = 0; node < 2; ++node){
      const float* q = &Qs[node][h*NHD];          // pre-scaled by 1/sqrt(HD), bias included
      const unsigned short* kr = &KVs[node*NM + m][h*NHD];
      float s = 0.f;
      #pragma unroll
      for (int j = 0; j < NHD; ++j) s += q[j] * bf2f(kr[j]);
      if (ms[node][m] == 0) s = -1e9f;
      float mx = s;
      #pragma unroll
      for (int off = 16; off; off >>= 1) mx = fmaxf(mx, __shfl_xor(mx, off, 32));
      const float e = __expf(s - mx);
      float sum = e;
      #pragma unroll
      for (int off = 16; off; off >>= 1) sum += __shfl_xor(sum, off, 32);
      Pw[node][h][m] = e / sum;
    }
  }
  __syncthreads();

  { // V = X * Wv^T + bv -> KVs (reuse)
    floatx4 acc[4][4] = {};
    for (int kk = 0; kk < 8; ++kk){
      short8 af[4], bf[4];
      #pragma unroll
      for (int t = 0; t < 4; ++t) af[t] = *(const short8*)&Xs[t*16 + ln][kk*32 + kh*8];
      #pragma unroll
      for (int t = 0; t < 4; ++t) bf[t] = *(const short8*)&Wv[(size_t)(wid*64 + t*16 + ln)*ND + kk*32 + kh*8];
      #pragma unroll
      for (int mt = 0; mt < 4; ++mt)
        #pragma unroll
        for (int nt = 0; nt < 4; ++nt)
          acc[mt][nt] = __builtin_amdgcn_mfma_f32_16x16x32_bf16(af[mt], bf[nt], acc[mt][nt], 0, 0, 0);
    }
    #pragma unroll
    for (int mt = 0; mt < 4; ++mt)
      #pragma unroll
      for (int nt = 0; nt < 4; ++nt){
        const int col = wid*64 + nt*16 + ln;
        const float bb = bv[col];
        #pragma unroll
        for (int r = 0; r < 4; ++r)
          KVs[mt*16 + kh*4 + r][col] = f2bf(acc[mt][nt][r] + bb);
      }
  }
  __syncthreads();

  { // PV: thread = output col d, loop nodes
    #pragma unroll
    for (int node = 0; node < 2; ++node){
      const float* aw = Pw[node][tid >> 5];
      float s = 0.f;
      #pragma unroll
      for (int m = 0; m < NM; ++m) s += aw[m] * bf2f(KVs[node*NM + m][tid]);
      att[(nid0 + node)*ND + tid] = f2bf(s);
    }
  }
}

// ---------------- LayerNorm kernels (1 wave per row, 4 rows per block) ---------------
__global__ __launch_bounds__(256) void ln_ff_kernel(const float* __restrict__ a,
    const float* __restrict__ b, const float* __restrict__ g, const float* __restrict__ be,
    unsigned short* __restrict__ out){
  const int row = blockIdx.x*4 + (threadIdx.x >> 6);
  const int lane = threadIdx.x & 63;
  const size_t base = (size_t)row*ND + lane*4;
  const float4 va = *(const float4*)(a + base);
  const float4 vb = *(const float4*)(b + base);
  float4 y = { va.x+vb.x, va.y+vb.y, va.z+vb.z, va.w+vb.w };
  float sum = y.x + y.y + y.z + y.w;
  #pragma unroll
  for (int off = 32; off; off >>= 1) sum += __shfl_xor(sum, off, 64);
  const float mu = sum * (1.f/ND);
  float4 d = { y.x-mu, y.y-mu, y.z-mu, y.w-mu };
  float ss = d.x*d.x + d.y*d.y + d.z*d.z + d.w*d.w;
  #pragma unroll
  for (int off = 32; off; off >>= 1) ss += __shfl_xor(ss, off, 64);
  const float rs = rsqrtf(ss * (1.f/ND) + 1e-5f);
  const float4 gv = *(const float4*)(g + lane*4);
  const float4 bv = *(const float4*)(be + lane*4);
  ushort4 o;
  o.x = f2bf(d.x*rs*gv.x + bv.x);
  o.y = f2bf(d.y*rs*gv.y + bv.y);
  o.z = f2bf(d.z*rs*gv.z + bv.z);
  o.w = f2bf(d.w*rs*gv.w + bv.w);
  *(ushort4*)(out + base) = o;
}

__global__ __launch_bounds__(256) void ln_final_kernel(const float* __restrict__ a,
    const unsigned short* __restrict__ xb, const float* __restrict__ g,
    const float* __restrict__ be, float* __restrict__ out){
  const int row = blockIdx.x*4 + (threadIdx.x >> 6);
  const int lane = threadIdx.x & 63;
  const size_t base = (size_t)row*ND + lane*4;
  const float4 va = *(const float4*)(a + base);
  const ushort4 xv = *(const ushort4*)(xb + base);
  float4 y = { va.x + bf2f(xv.x), va.y + bf2f(xv.y), va.z + bf2f(xv.z), va.w + bf2f(xv.w) };
  float sum = y.x + y.y + y.z + y.w;
  #pragma unroll
  for (int off = 32; off; off >>= 1) sum += __shfl_xor(sum, off, 64);
  const float mu = sum * (1.f/ND);
  float4 d = { y.x-mu, y.y-mu, y.z-mu, y.w-mu };
  float ss = d.x*d.x + d.y*d.y + d.z*d.z + d.w*d.w;
  #pragma unroll
  for (int off = 32; off; off >>= 1) ss += __shfl_xor(ss, off, 64);
  const float rs = rsqrtf(ss * (1.f/ND) + 1e-5f);
  const float4 gv = *(const float4*)(g + lane*4);
  const float4 bv = *(const float4*)(be + lane*4);
  float4 o = { d.x*rs*gv.x + bv.x, d.y*rs*gv.y + bv.y, d.z*rs*gv.z + bv.z, d.w*rs*gv.w + bv.w };
  *(float4*)(out + base) = o;
}

// ---------------- launch ----------------
extern "C" void kernel_launch(void* const* d_in, const int* in_sizes, int n_in,
                              void* d_out, int out_size, void* d_ws, size_t ws_size,
                              hipStream_t stream){
  const float* node  = (const float*)d_in[0];
  const float* neigh = (const float*)d_in[1];
  const int*   maskp = (const int*)d_in[2];
  const float* Wq = (const float*)d_in[3];  const float* bq = (const float*)d_in[4];
  const float* Wk = (const float*)d_in[5];  const float* bk = (const float*)d_in[6];
  const float* Wv = (const float*)d_in[7];  const float* bv = (const float*)d_in[8];
  const float* Wo = (const float*)d_in[9];  const float* bo = (const float*)d_in[10];
  const float* g1 = (const float*)d_in[11]; const float* be1 = (const float*)d_in[12];
  const float* W1 = (const float*)d_in[13]; const float* b1 = (const float*)d_in[14];
  const float* W2 = (const float*)d_in[15]; const float* b2 = (const float*)d_in[16];
  const float* g2 = (const float*)d_in[17]; const float* be2 = (const float*)d_in[18];

  char* ws = (char*)d_ws;
  size_t o = 0;
  unsigned short* wq_b = (unsigned short*)(ws + o); o += (size_t)ND*ND*2;
  unsigned short* wk_b = (unsigned short*)(ws + o); o += (size_t)ND*ND*2;
  unsigned short* wv_b = (unsigned short*)(ws + o); o += (size_t)ND*ND*2;
  unsigned short* wo_b = (unsigned short*)(ws + o); o += (size_t)ND*ND*2;
  unsigned short* w1_b = (unsigned short*)(ws + o); o += (size_t)NFF*ND*2;
  unsigned short* w2_b = (unsigned short*)(ws + o); o += (size_t)NFF*ND*2;
  char* regA = ws + o;                  // 24MB: node_bf16[8] + Q[16]; later t1[16]; later h
  char* regB = regA + 25165824;         // 8MB: h tail (h = 32MB spanning A+B)
  char* regC = regB + 8388608;          // 8MB: attended; later t2 (16MB spanning C+D)
  char* regD = regC + 8388608;          // 8MB
  char* regE = regD + 8388608;          // 8MB: x bf16
  const size_t need = (size_t)(regE - ws) + 8388608;
  if (ws_size < need) return;           // fail visibly rather than corrupt

  unsigned short* node_b = (unsigned short*)regA;
  float* Qp   = (float*)(regA + 8388608);
  float* t1   = (float*)regA;
  unsigned short* hbuf = (unsigned short*)regA;
  unsigned short* attb = (unsigned short*)regC;
  float* t2   = (float*)regC;
  unsigned short* xb  = (unsigned short*)regE;

  // converts
  cvt_bf16<<<dim3(4096), 256, 0, stream>>>(node, node_b, NROWS*ND/4);
  cvt_bf16<<<dim3(64),   256, 0, stream>>>(Wq, wq_b, ND*ND/4);
  cvt_bf16<<<dim3(64),   256, 0, stream>>>(Wk, wk_b, ND*ND/4);
  cvt_bf16<<<dim3(64),   256, 0, stream>>>(Wv, wv_b, ND*ND/4);
  cvt_bf16<<<dim3(64),   256, 0, stream>>>(Wo, wo_b, ND*ND/4);
  cvt_bf16<<<dim3(256),  256, 0, stream>>>(W1, w1_b, NFF*ND/4);
  cvt_bf16<<<dim3(256),  256, 0, stream>>>(W2, w2_b, NFF*ND/4);

  // Q = (node @ Wq^T + bq) / sqrt(HD)
  gemm_bt<0><<<dim3(NROWS/128, ND/128), 256, 0, stream>>>(node_b, wq_b, bq, Qp,
      NROWS, ND, ND, 0.17677669529663687f);
  // fused K/V/attention
  attn_kernel<<<dim3(NROWS/2), 256, 0, stream>>>(neigh, maskp, wk_b, wv_b, bk, bv, Qp, attb);
  // t1 = attended @ Wo^T + bo
  gemm_bt<1><<<dim3(NROWS/128, ND/128), 256, 0, stream>>>(attb, wo_b, bo, t1,
      NROWS, ND, ND, 1.f);
  // x = LN1(node + t1) -> bf16
  ln_ff_kernel<<<dim3(NROWS/4), 256, 0, stream>>>(node, t1, g1, be1, xb);
  // h = relu(x @ W1^T + b1) -> bf16
  gemm_bt<2><<<dim3(NROWS/128, NFF/128), 256, 0, stream>>>(xb, w1_b, b1, hbuf,
      NROWS, NFF, ND, 1.f);
  // t2 = h @ W2^T + b2
  gemm_bt<1><<<dim3(NROWS/128, ND/128), 256, 0, stream>>>(hbuf, w2_b, b2, t2,
      NROWS, ND, NFF, 1.f);
  // out = LN2(x + t2)
  ln_final_kernel<<<dim3(NROWS/4), 256, 0, stream>>>(t2, xb, g2, be2, (float*)d_out);
}

// Round 2
// 431.300 us; speedup vs baseline: 1.3051x; 1.3051x over previous
//
#include <hip/hip_runtime.h>

#define NB 2
#define NN 8192
#define NM 32
#define ND 256
#define NH 8
#define NHD 32
#define NFF 1024
#define NROWS (NB*NN)   // 16384

typedef __attribute__((ext_vector_type(8))) short short8;
typedef __attribute__((ext_vector_type(4))) float floatx4;

__device__ __forceinline__ unsigned short f2bf(float f){
  unsigned u = __float_as_uint(f);
  u += 0x7fffu + ((u >> 16) & 1u);
  return (unsigned short)(u >> 16);
}
__device__ __forceinline__ float bf2f(unsigned short s){
  return __uint_as_float(((unsigned)s) << 16);
}

// ---------------- f32 -> bf16 convert ----------------
__global__ __launch_bounds__(256) void cvt_bf16(const float* __restrict__ in,
                                                unsigned short* __restrict__ out, int n4){
  int i = blockIdx.x * 256 + threadIdx.x;
  if (i >= n4) return;
  float4 v = ((const float4*)in)[i];
  ushort4 o;
  o.x = f2bf(v.x); o.y = f2bf(v.y); o.z = f2bf(v.z); o.w = f2bf(v.w);
  ((ushort4*)out)[i] = o;
}

// ---------------- GEMM: C = A[Mr x K](bf16) * W[Nc x K](bf16)^T + bias, epilogues ----
// EPI 0: (acc+bias)*scale -> f32 ; EPI 1: acc+bias -> f32 ; EPI 2: relu(acc+bias) -> bf16
template<int EPI>
__global__ __launch_bounds__(256) void gemm_bt(const unsigned short* __restrict__ A,
    const unsigned short* __restrict__ W, const float* __restrict__ bias,
    void* __restrict__ out, int Mr, int Nc, int K, float scale){
  __shared__ unsigned short As[128][40];   // +8 pad: 80B stride -> conflict-free b128
  __shared__ unsigned short Bs[128][40];
  const int tid = threadIdx.x;
  const int wid = tid >> 6, lane = tid & 63, ln = lane & 15, kh = lane >> 4;
  const int wr = (wid >> 1) * 64, wc = (wid & 1) * 64;
  const int row0 = blockIdx.x * 128, col0 = blockIdx.y * 128;
  const int lr = tid >> 2, lc = (tid & 3) * 8;
  floatx4 acc[4][4] = {};
  for (int k0 = 0; k0 < K; k0 += 32){
    __syncthreads();
    *(short8*)&As[lr][lc]    = *(const short8*)&A[(size_t)(row0+lr)*K + k0 + lc];
    *(short8*)&As[lr+64][lc] = *(const short8*)&A[(size_t)(row0+lr+64)*K + k0 + lc];
    *(short8*)&Bs[lr][lc]    = *(const short8*)&W[(size_t)(col0+lr)*K + k0 + lc];
    *(short8*)&Bs[lr+64][lc] = *(const short8*)&W[(size_t)(col0+lr+64)*K + k0 + lc];
    __syncthreads();
    short8 af[4], bf[4];
    #pragma unroll
    for (int t = 0; t < 4; ++t) af[t] = *(const short8*)&As[wr + t*16 + ln][kh*8];
    #pragma unroll
    for (int t = 0; t < 4; ++t) bf[t] = *(const short8*)&Bs[wc + t*16 + ln][kh*8];
    #pragma unroll
    for (int mt = 0; mt < 4; ++mt)
      #pragma unroll
      for (int nt = 0; nt < 4; ++nt)
        acc[mt][nt] = __builtin_amdgcn_mfma_f32_16x16x32_bf16(af[mt], bf[nt], acc[mt][nt], 0, 0, 0);
  }
  #pragma unroll
  for (int mt = 0; mt < 4; ++mt){
    #pragma unroll
    for (int nt = 0; nt < 4; ++nt){
      const int gc = col0 + wc + nt*16 + ln;
      const float bs = bias[gc];
      #pragma unroll
      for (int r = 0; r < 4; ++r){
        const int gr = row0 + wr + mt*16 + kh*4 + r;
        float v = acc[mt][nt][r] + bs;
        if (EPI == 0)      ((float*)out)[(size_t)gr*Nc + gc] = v * scale;
        else if (EPI == 1) ((float*)out)[(size_t)gr*Nc + gc] = v;
        else               ((unsigned short*)out)[(size_t)gr*Nc + gc] = f2bf(fmaxf(v, 0.f));
      }
    }
  }
}

// ---------------- fused neighbor attention: 2 nodes per WG, 8 waves ----------------
__global__ __launch_bounds__(512, 4) void attn_kernel(
    const float* __restrict__ neigh, const int* __restrict__ mask,
    const unsigned short* __restrict__ Wk, const unsigned short* __restrict__ Wv,
    const float* __restrict__ bk, const float* __restrict__ bv,
    const float* __restrict__ Qw, unsigned short* __restrict__ att){
  __shared__ unsigned short Xs[64][264];   // 2 nodes x 32 m, bf16, padded (528B stride)
  __shared__ unsigned short KVs[64][264];  // K then V (reused)
  __shared__ float Qs[2][ND];
  __shared__ float Pw[2][NH][NM];
  __shared__ int ms[2][NM];
  const int tid = threadIdx.x;
  const int wid = tid >> 6, lane = tid & 63, ln = lane & 15, kh = lane >> 4;
  const size_t nid0 = (size_t)blockIdx.x * 2;

  // --- prefetch K-weight fragments for this wave's 32-col slice (L2-hot) ---
  // issued BEFORE staging so their latency hides under the HBM reads
  short8 wkf[8][2];
  #pragma unroll
  for (int kk = 0; kk < 8; ++kk)
    #pragma unroll
    for (int nt = 0; nt < 2; ++nt)
      wkf[kk][nt] = *(const short8*)&Wk[(size_t)(wid*32 + nt*16 + ln)*ND + kk*32 + kh*8];

  { // stage X (f32 -> bf16), Q, mask
    const float4* src = (const float4*)(neigh + nid0 * (NM*ND));
    #pragma unroll
    for (int it = 0; it < 8; ++it){
      const int i = tid + it*512;
      const int r = i >> 6, c = (i & 63) * 4;
      const float4 v = src[i];
      ushort4 o; o.x = f2bf(v.x); o.y = f2bf(v.y); o.z = f2bf(v.z); o.w = f2bf(v.w);
      *(ushort4*)&Xs[r][c] = o;
    }
    if (tid < 128) ((float4*)&Qs[0][0])[tid] = ((const float4*)(Qw + nid0*ND))[tid];
    if (tid < 64)  ms[tid>>5][tid&31] = mask[nid0*NM + tid];
  }
  __syncthreads();   // B1

  { // K = X * Wk^T + bk  -> KVs (bf16). wave owns 32 output cols
    floatx4 acc[4][2] = {};
    #pragma unroll
    for (int kk = 0; kk < 8; ++kk){
      short8 af[4];
      #pragma unroll
      for (int mt = 0; mt < 4; ++mt) af[mt] = *(const short8*)&Xs[mt*16 + ln][kk*32 + kh*8];
      #pragma unroll
      for (int mt = 0; mt < 4; ++mt)
        #pragma unroll
        for (int nt = 0; nt < 2; ++nt)
          acc[mt][nt] = __builtin_amdgcn_mfma_f32_16x16x32_bf16(af[mt], wkf[kk][nt], acc[mt][nt], 0, 0, 0);
    }
    #pragma unroll
    for (int nt = 0; nt < 2; ++nt){
      const int col = wid*32 + nt*16 + ln;
      const float bb = bk[col];
      #pragma unroll
      for (int mt = 0; mt < 4; ++mt)
        #pragma unroll
        for (int r = 0; r < 4; ++r)
          KVs[mt*16 + kh*4 + r][col] = f2bf(acc[mt][nt][r] + bb);
    }
  }

  // --- prefetch V-weight fragments; latency drains across softmax phase ---
  short8 wvf[8][2];
  #pragma unroll
  for (int kk = 0; kk < 8; ++kk)
    #pragma unroll
    for (int nt = 0; nt < 2; ++nt)
      wvf[kk][nt] = *(const short8*)&Wv[(size_t)(wid*32 + nt*16 + ln)*ND + kk*32 + kh*8];

  __syncthreads();   // B2

  { // scores + softmax: one thread per (node, h, m)
    const int node = tid >> 8, h = (tid >> 5) & 7, m = tid & 31;
    const float* q = &Qs[node][h*NHD];          // pre-scaled by 1/sqrt(HD), bias included
    const unsigned short* kr = &KVs[node*NM + m][h*NHD];
    float s = 0.f;
    #pragma unroll
    for (int j4 = 0; j4 < 4; ++j4){
      const short8 kv = *(const short8*)&kr[j4*8];
      #pragma unroll
      for (int j = 0; j < 8; ++j) s += q[j4*8+j] * bf2f((unsigned short)kv[j]);
    }
    if (ms[node][m] == 0) s = -1e9f;
    float mx = s;
    #pragma unroll
    for (int off = 16; off; off >>= 1) mx = fmaxf(mx, __shfl_xor(mx, off, 32));
    const float e = __expf(s - mx);
    float sum = e;
    #pragma unroll
    for (int off = 16; off; off >>= 1) sum += __shfl_xor(sum, off, 32);
    Pw[node][h][m] = e / sum;
  }
  __syncthreads();   // B3

  { // V = X * Wv^T + bv -> KVs (reuse)
    floatx4 acc[4][2] = {};
    #pragma unroll
    for (int kk = 0; kk < 8; ++kk){
      short8 af[4];
      #pragma unroll
      for (int mt = 0; mt < 4; ++mt) af[mt] = *(const short8*)&Xs[mt*16 + ln][kk*32 + kh*8];
      #pragma unroll
      for (int mt = 0; mt < 4; ++mt)
        #pragma unroll
        for (int nt = 0; nt < 2; ++nt)
          acc[mt][nt] = __builtin_amdgcn_mfma_f32_16x16x32_bf16(af[mt], wvf[kk][nt], acc[mt][nt], 0, 0, 0);
    }
    #pragma unroll
    for (int nt = 0; nt < 2; ++nt){
      const int col = wid*32 + nt*16 + ln;
      const float bb = bv[col];
      #pragma unroll
      for (int mt = 0; mt < 4; ++mt)
        #pragma unroll
        for (int r = 0; r < 4; ++r)
          KVs[mt*16 + kh*4 + r][col] = f2bf(acc[mt][nt][r] + bb);
    }
  }
  __syncthreads();   // B4

  { // PV: one thread per (node, d)
    const int node = tid >> 8, d = tid & 255;
    const float* aw = Pw[node][d >> 5];
    float s = 0.f;
    #pragma unroll
    for (int m = 0; m < NM; ++m) s += aw[m] * bf2f(KVs[node*NM + m][d]);
    att[(nid0 + node)*ND + d] = f2bf(s);
  }
}

// ---------------- LayerNorm kernels (1 wave per row, 4 rows per block) ---------------
__global__ __launch_bounds__(256) void ln_ff_kernel(const float* __restrict__ a,
    const float* __restrict__ b, const float* __restrict__ g, const float* __restrict__ be,
    unsigned short* __restrict__ out){
  const int row = blockIdx.x*4 + (threadIdx.x >> 6);
  const int lane = threadIdx.x & 63;
  const size_t base = (size_t)row*ND + lane*4;
  const float4 va = *(const float4*)(a + base);
  const float4 vb = *(const float4*)(b + base);
  float4 y = { va.x+vb.x, va.y+vb.y, va.z+vb.z, va.w+vb.w };
  float sum = y.x + y.y + y.z + y.w;
  #pragma unroll
  for (int off = 32; off; off >>= 1) sum += __shfl_xor(sum, off, 64);
  const float mu = sum * (1.f/ND);
  float4 d = { y.x-mu, y.y-mu, y.z-mu, y.w-mu };
  float ss = d.x*d.x + d.y*d.y + d.z*d.z + d.w*d.w;
  #pragma unroll
  for (int off = 32; off; off >>= 1) ss += __shfl_xor(ss, off, 64);
  const float rs = rsqrtf(ss * (1.f/ND) + 1e-5f);
  const float4 gv = *(const float4*)(g + lane*4);
  const float4 bv = *(const float4*)(be + lane*4);
  ushort4 o;
  o.x = f2bf(d.x*rs*gv.x + bv.x);
  o.y = f2bf(d.y*rs*gv.y + bv.y);
  o.z = f2bf(d.z*rs*gv.z + bv.z);
  o.w = f2bf(d.w*rs*gv.w + bv.w);
  *(ushort4*)(out + base) = o;
}

__global__ __launch_bounds__(256) void ln_final_kernel(const float* __restrict__ a,
    const unsigned short* __restrict__ xb, const float* __restrict__ g,
    const float* __restrict__ be, float* __restrict__ out){
  const int row = blockIdx.x*4 + (threadIdx.x >> 6);
  const int lane = threadIdx.x & 63;
  const size_t base = (size_t)row*ND + lane*4;
  const float4 va = *(const float4*)(a + base);
  const ushort4 xv = *(const ushort4*)(xb + base);
  float4 y = { va.x + bf2f(xv.x), va.y + bf2f(xv.y), va.z + bf2f(xv.z), va.w + bf2f(xv.w) };
  float sum = y.x + y.y + y.z + y.w;
  #pragma unroll
  for (int off = 32; off; off >>= 1) sum += __shfl_xor(sum, off, 64);
  const float mu = sum * (1.f/ND);
  float4 d = { y.x-mu, y.y-mu, y.z-mu, y.w-mu };
  float ss = d.x*d.x + d.y*d.y + d.z*d.z + d.w*d.w;
  #pragma unroll
  for (int off = 32; off; off >>= 1) ss += __shfl_xor(ss, off, 64);
  const float rs = rsqrtf(ss * (1.f/ND) + 1e-5f);
  const float4 gv = *(const float4*)(g + lane*4);
  const float4 bv = *(const float4*)(be + lane*4);
  float4 o = { d.x*rs*gv.x + bv.x, d.y*rs*gv.y + bv.y, d.z*rs*gv.z + bv.z, d.w*rs*gv.w + bv.w };
  *(float4*)(out + base) = o;
}

// ---------------- launch ----------------
extern "C" void kernel_launch(void* const* d_in, const int* in_sizes, int n_in,
                              void* d_out, int out_size, void* d_ws, size_t ws_size,
                              hipStream_t stream){
  const float* node  = (const float*)d_in[0];
  const float* neigh = (const float*)d_in[1];
  const int*   maskp = (const int*)d_in[2];
  const float* Wq = (const float*)d_in[3];  const float* bq = (const float*)d_in[4];
  const float* Wk = (const float*)d_in[5];  const float* bk = (const float*)d_in[6];
  const float* Wv = (const float*)d_in[7];  const float* bv = (const float*)d_in[8];
  const float* Wo = (const float*)d_in[9];  const float* bo = (const float*)d_in[10];
  const float* g1 = (const float*)d_in[11]; const float* be1 = (const float*)d_in[12];
  const float* W1 = (const float*)d_in[13]; const float* b1 = (const float*)d_in[14];
  const float* W2 = (const float*)d_in[15]; const float* b2 = (const float*)d_in[16];
  const float* g2 = (const float*)d_in[17]; const float* be2 = (const float*)d_in[18];

  char* ws = (char*)d_ws;
  size_t o = 0;
  unsigned short* wq_b = (unsigned short*)(ws + o); o += (size_t)ND*ND*2;
  unsigned short* wk_b = (unsigned short*)(ws + o); o += (size_t)ND*ND*2;
  unsigned short* wv_b = (unsigned short*)(ws + o); o += (size_t)ND*ND*2;
  unsigned short* wo_b = (unsigned short*)(ws + o); o += (size_t)ND*ND*2;
  unsigned short* w1_b = (unsigned short*)(ws + o); o += (size_t)NFF*ND*2;
  unsigned short* w2_b = (unsigned short*)(ws + o); o += (size_t)NFF*ND*2;
  char* regA = ws + o;                  // 24MB: node_bf16[8] + Q[16]; later t1[16]; later h
  char* regB = regA + 25165824;         // 8MB: h tail (h = 32MB spanning A+B)
  char* regC = regB + 8388608;          // 8MB: attended; later t2 (16MB spanning C+D)
  char* regD = regC + 8388608;          // 8MB
  char* regE = regD + 8388608;          // 8MB: x bf16
  const size_t need = (size_t)(regE - ws) + 8388608;
  if (ws_size < need) return;           // fail visibly rather than corrupt

  unsigned short* node_b = (unsigned short*)regA;
  float* Qp   = (float*)(regA + 8388608);
  float* t1   = (float*)regA;
  unsigned short* hbuf = (unsigned short*)regA;
  unsigned short* attb = (unsigned short*)regC;
  float* t2   = (float*)regC;
  unsigned short* xb  = (unsigned short*)regE;

  // converts
  cvt_bf16<<<dim3(4096), 256, 0, stream>>>(node, node_b, NROWS*ND/4);
  cvt_bf16<<<dim3(64),   256, 0, stream>>>(Wq, wq_b, ND*ND/4);
  cvt_bf16<<<dim3(64),   256, 0, stream>>>(Wk, wk_b, ND*ND/4);
  cvt_bf16<<<dim3(64),   256, 0, stream>>>(Wv, wv_b, ND*ND/4);
  cvt_bf16<<<dim3(64),   256, 0, stream>>>(Wo, wo_b, ND*ND/4);
  cvt_bf16<<<dim3(256),  256, 0, stream>>>(W1, w1_b, NFF*ND/4);
  cvt_bf16<<<dim3(256),  256, 0, stream>>>(W2, w2_b, NFF*ND/4);

  // Q = (node @ Wq^T + bq) / sqrt(HD)
  gemm_bt<0><<<dim3(NROWS/128, ND/128), 256, 0, stream>>>(node_b, wq_b, bq, Qp,
      NROWS, ND, ND, 0.17677669529663687f);
  // fused K/V/attention
  attn_kernel<<<dim3(NROWS/2), 512, 0, stream>>>(neigh, maskp, wk_b, wv_b, bk, bv, Qp, attb);
  // t1 = attended @ Wo^T + bo
  gemm_bt<1><<<dim3(NROWS/128, ND/128), 256, 0, stream>>>(attb, wo_b, bo, t1,
      NROWS, ND, ND, 1.f);
  // x = LN1(node + t1) -> bf16
  ln_ff_kernel<<<dim3(NROWS/4), 256, 0, stream>>>(node, t1, g1, be1, xb);
  // h = relu(x @ W1^T + b1) -> bf16
  gemm_bt<2><<<dim3(NROWS/128, NFF/128), 256, 0, stream>>>(xb, w1_b, b1, hbuf,
      NROWS, NFF, ND, 1.f);
  // t2 = h @ W2^T + b2
  gemm_bt<1><<<dim3(NROWS/128, ND/128), 256, 0, stream>>>(hbuf, w2_b, b2, t2,
      NROWS, ND, NFF, 1.f);
  // out = LN2(x + t2)
  ln_final_kernel<<<dim3(NROWS/4), 256, 0, stream>>>(t2, xb, g2, be2, (float*)d_out);
}

// Round 3
// 374.844 us; speedup vs baseline: 1.5017x; 1.1506x over previous
//
#include <hip/hip_runtime.h>

#define NM 32
#define ND 256
#define NH 8
#define NFF 1024
#define NROWS 16384

typedef __attribute__((ext_vector_type(8))) short short8;
typedef __attribute__((ext_vector_type(4))) float floatx4;

__device__ __forceinline__ unsigned short f2bf(float f){
  unsigned u = __float_as_uint(f);
  u += 0x7fffu + ((u >> 16) & 1u);
  return (unsigned short)(u >> 16);
}
__device__ __forceinline__ float bf2f(unsigned short s){
  return __uint_as_float(((unsigned)s) << 16);
}

// ---------------- f32 -> bf16 convert ----------------
__global__ __launch_bounds__(256) void cvt_bf16(const float* __restrict__ in,
                                                unsigned short* __restrict__ out, int n4){
  int i = blockIdx.x * 256 + threadIdx.x;
  if (i >= n4) return;
  float4 v = ((const float4*)in)[i];
  ushort4 o;
  o.x = f2bf(v.x); o.y = f2bf(v.y); o.z = f2bf(v.z); o.w = f2bf(v.w);
  ((ushort4*)out)[i] = o;
}

// ---------------- Wk transpose + cvt: Wkt[e][c] = Wk[c][e] (bf16) -------------
__global__ __launch_bounds__(256) void transpose_cvt(const float* __restrict__ in,
    unsigned short* __restrict__ out){
  __shared__ float T[32][33];
  const int ti = blockIdx.x >> 3, tj = blockIdx.x & 7;
  const int tid = threadIdx.x;
  {
    const int r = tid >> 3, c4 = (tid & 7) * 4;
    const float4 v = *(const float4*)&in[(ti*32 + r)*256 + tj*32 + c4];
    T[r][c4+0] = v.x; T[r][c4+1] = v.y; T[r][c4+2] = v.z; T[r][c4+3] = v.w;
  }
  __syncthreads();
  {
    const int cc = tid >> 3, r4 = (tid & 7) * 4;
    ushort4 o;
    o.x = f2bf(T[r4+0][cc]); o.y = f2bf(T[r4+1][cc]);
    o.z = f2bf(T[r4+2][cc]); o.w = f2bf(T[r4+3][cc]);
    *(ushort4*)&out[(tj*32 + cc)*256 + ti*32 + r4] = o;
  }
}

// ---------------- Wvo_t[j][f=(h,e)] = sum_cc Wv[h*32+cc][e] * Wo[j][h*32+cc] ---
__global__ __launch_bounds__(256) void wvo_kernel(const float* __restrict__ Wv,
    const float* __restrict__ Wo, unsigned short* __restrict__ wvo_t){
  __shared__ float WoL[256][33];
  __shared__ float wvv[32];
  const int f = blockIdx.x, h = f >> 8, e = f & 255;
  const int tid = threadIdx.x;
  for (int idx = tid; idx < 8192; idx += 256){
    const int j = idx >> 5, cc = idx & 31;
    WoL[j][cc] = Wo[j*256 + h*32 + cc];
  }
  if (tid < 32) wvv[tid] = Wv[(h*32 + tid)*256 + e];
  __syncthreads();
  float s = 0.f;
  #pragma unroll
  for (int cc = 0; cc < 32; ++cc) s += WoL[tid][cc] * wvv[cc];
  wvo_t[(size_t)tid*2048 + f] = f2bf(s);
}

// ---------------- bvo[j] = bo[j] + sum_c bv[c]*Wo[j][c] ----------------
__global__ __launch_bounds__(256) void bvo_kernel(const float* __restrict__ bv,
    const float* __restrict__ bo, const float* __restrict__ Wo, float* __restrict__ bvo){
  const int j = threadIdx.x;
  float s = bo[j];
  for (int c = 0; c < 256; ++c) s += bv[c] * Wo[j*256 + c];
  bvo[j] = s;
}

// ---------------- GEMM: out = A[.. x K] * W[Nc x K]^T + bias -> bf16 ----------
// EPI 0: relu((acc+bias))        -> bf16
// EPI 1: (acc+bias)*scale        -> bf16
template<int EPI>
__global__ __launch_bounds__(256) void gemm_bt(const unsigned short* __restrict__ A,
    const unsigned short* __restrict__ W, const float* __restrict__ bias,
    unsigned short* __restrict__ out, int Nc, int K, float scale){
  __shared__ unsigned short As[128][40];
  __shared__ unsigned short Bs[128][40];
  const int tid = threadIdx.x;
  const int wid = tid >> 6, lane = tid & 63, ln = lane & 15, kh = lane >> 4;
  const int wr = (wid >> 1) * 64, wc = (wid & 1) * 64;
  const int row0 = blockIdx.x * 128, col0 = blockIdx.y * 128;
  const int lr = tid >> 2, lc = (tid & 3) * 8;
  floatx4 acc[4][4] = {};
  for (int k0 = 0; k0 < K; k0 += 32){
    __syncthreads();
    *(short8*)&As[lr][lc]    = *(const short8*)&A[(size_t)(row0+lr)*K + k0 + lc];
    *(short8*)&As[lr+64][lc] = *(const short8*)&A[(size_t)(row0+lr+64)*K + k0 + lc];
    *(short8*)&Bs[lr][lc]    = *(const short8*)&W[(size_t)(col0+lr)*K + k0 + lc];
    *(short8*)&Bs[lr+64][lc] = *(const short8*)&W[(size_t)(col0+lr+64)*K + k0 + lc];
    __syncthreads();
    short8 af[4], bf[4];
    #pragma unroll
    for (int t = 0; t < 4; ++t) af[t] = *(const short8*)&As[wr + t*16 + ln][kh*8];
    #pragma unroll
    for (int t = 0; t < 4; ++t) bf[t] = *(const short8*)&Bs[wc + t*16 + ln][kh*8];
    #pragma unroll
    for (int mt = 0; mt < 4; ++mt)
      #pragma unroll
      for (int nt = 0; nt < 4; ++nt)
        acc[mt][nt] = __builtin_amdgcn_mfma_f32_16x16x32_bf16(af[mt], bf[nt], acc[mt][nt], 0, 0, 0);
  }
  #pragma unroll
  for (int mt = 0; mt < 4; ++mt){
    #pragma unroll
    for (int nt = 0; nt < 4; ++nt){
      const int gc = col0 + wc + nt*16 + ln;
      const float bs = bias[gc];
      #pragma unroll
      for (int r = 0; r < 4; ++r){
        const int gr = row0 + wr + mt*16 + kh*4 + r;
        float v = acc[mt][nt][r] + bs;
        if (EPI == 0) out[(size_t)gr*Nc + gc] = f2bf(fmaxf(v, 0.f));
        else          out[(size_t)gr*Nc + gc] = f2bf(v * scale);
      }
    }
  }
}

// ---------------- qk GEMM (per head, K=32): qk[n][h*256+e] = Qb[n][h-slice]@Wkt[e][h-slice]
__global__ __launch_bounds__(256) void gemm_qk(const unsigned short* __restrict__ A,
    const unsigned short* __restrict__ Wkt, unsigned short* __restrict__ out){
  __shared__ unsigned short As[128][40];
  __shared__ unsigned short Bs[128][40];
  const int tid = threadIdx.x;
  const int wid = tid >> 6, lane = tid & 63, ln = lane & 15, kh = lane >> 4;
  const int wr = (wid >> 1) * 64, wc = (wid & 1) * 64;
  const int row0 = blockIdx.x * 128, col0 = blockIdx.y * 128, h = blockIdx.z;
  #pragma unroll
  for (int it = 0; it < 2; ++it){
    const int flat = it*256 + tid;
    const int r = flat >> 2, c = flat & 3;
    *(short8*)&As[r][c*8] = *(const short8*)&A[(size_t)(row0+r)*256 + h*32 + c*8];
    *(short8*)&Bs[r][c*8] = *(const short8*)&Wkt[(size_t)(col0+r)*256 + h*32 + c*8];
  }
  __syncthreads();
  short8 af[4], bf[4];
  #pragma unroll
  for (int t = 0; t < 4; ++t) af[t] = *(const short8*)&As[wr + t*16 + ln][kh*8];
  #pragma unroll
  for (int t = 0; t < 4; ++t) bf[t] = *(const short8*)&Bs[wc + t*16 + ln][kh*8];
  floatx4 acc[4][4] = {};
  #pragma unroll
  for (int mt = 0; mt < 4; ++mt)
    #pragma unroll
    for (int nt = 0; nt < 4; ++nt)
      acc[mt][nt] = __builtin_amdgcn_mfma_f32_16x16x32_bf16(af[mt], bf[nt], acc[mt][nt], 0, 0, 0);
  #pragma unroll
  for (int mt = 0; mt < 4; ++mt)
    #pragma unroll
    for (int nt = 0; nt < 4; ++nt)
      #pragma unroll
      for (int r = 0; r < 4; ++r)
        out[(size_t)(row0 + wr + mt*16 + kh*4 + r)*2048 + h*256 + col0 + wc + nt*16 + ln]
            = f2bf(acc[mt][nt][r]);
}

// ---------------- fused attention: 1 wave = 1 node, no barriers ----------------
// scores MFMA (X @ qk^T), in-fragment softmax, VALU Pbar = P @ X -> bf16
__global__ __launch_bounds__(256) void attn2_kernel(const float* __restrict__ neigh,
    const int* __restrict__ mask, const unsigned short* __restrict__ qk,
    unsigned short* __restrict__ pbar, int n0){
  __shared__ unsigned short Xs[4][8192];   // XOR-swizzled 16B slots
  __shared__ float Pl[4][32][8];
  __shared__ float Mf[4][32];
  const int tid = threadIdx.x;
  const int wid = tid >> 6, lane = tid & 63;
  const int ln = lane & 15, kh = lane >> 4;
  const int nloc = blockIdx.x * 4 + wid;
  const size_t nid = (size_t)n0 + nloc;
  unsigned short* X = Xs[wid];

  // qk B-fragments from global (L2/HBM), issued early
  short8 bfrag[8];
  const unsigned short* qkn = qk + (size_t)nloc*2048 + (size_t)(ln & 7)*256;
  #pragma unroll
  for (int kk = 0; kk < 8; ++kk) bfrag[kk] = *(const short8*)&qkn[kk*32 + kh*8];

  if (lane < 32) Mf[wid][lane] = mask[nid*NM + lane] ? 0.f : -1e9f;

  // stage X (32x256 f32 -> bf16, swizzled)
  const float* xg = neigh + nid * (NM*ND);
  #pragma unroll
  for (int i = 0; i < 16; ++i){
    const int flat8 = i*64 + lane;
    const int m = flat8 >> 5, ec = flat8 & 31;
    const float4 a = *(const float4*)&xg[flat8*8];
    const float4 b = *(const float4*)&xg[flat8*8 + 4];
    short8 v;
    v[0]=(short)f2bf(a.x); v[1]=(short)f2bf(a.y); v[2]=(short)f2bf(a.z); v[3]=(short)f2bf(a.w);
    v[4]=(short)f2bf(b.x); v[5]=(short)f2bf(b.y); v[6]=(short)f2bf(b.z); v[7]=(short)f2bf(b.w);
    *(short8*)&X[m*256 + ((ec ^ (m & 31)) << 3)] = v;
  }

  // scores [32m x 16h] = X @ qk^T   (cols 8..15 are duplicates, ignored)
  floatx4 acc0 = {}, acc1 = {};
  #pragma unroll
  for (int kk = 0; kk < 8; ++kk){
    const int slot = kk*4 + kh;
    const int m0 = ln, m1 = 16 + ln;
    const short8 a0 = *(const short8*)&X[m0*256 + ((slot ^ (m0 & 31)) << 3)];
    const short8 a1 = *(const short8*)&X[m1*256 + ((slot ^ (m1 & 31)) << 3)];
    acc0 = __builtin_amdgcn_mfma_f32_16x16x32_bf16(a0, bfrag[kk], acc0, 0, 0, 0);
    acc1 = __builtin_amdgcn_mfma_f32_16x16x32_bf16(a1, bfrag[kk], acc1, 0, 0, 0);
  }

  // softmax over m (rows) per head h=ln; rows live on lanes {ln, ln+16, ln+32, ln+48}
  float p8[8]; float mx = -3.0e38f;
  #pragma unroll
  for (int r = 0; r < 4; ++r){
    const float s0 = acc0[r] + Mf[wid][kh*4 + r];
    const float s1 = acc1[r] + Mf[wid][16 + kh*4 + r];
    p8[r] = s0; p8[4+r] = s1;
    mx = fmaxf(mx, fmaxf(s0, s1));
  }
  mx = fmaxf(mx, __shfl_xor(mx, 16));
  mx = fmaxf(mx, __shfl_xor(mx, 32));
  float sum = 0.f;
  #pragma unroll
  for (int k = 0; k < 8; ++k){ p8[k] = __expf(p8[k] - mx); sum += p8[k]; }
  sum += __shfl_xor(sum, 16);
  sum += __shfl_xor(sum, 32);
  const float inv = 1.f / sum;
  if (ln < 8){
    #pragma unroll
    for (int r = 0; r < 4; ++r){
      Pl[wid][kh*4 + r][ln]      = p8[r]   * inv;
      Pl[wid][16 + kh*4 + r][ln] = p8[4+r] * inv;
    }
  }

  // Pbar[h][e] = sum_m P[h][m] * X[m][e]; lane = (hh, ec): 4 heads x 8 elems
  const int hh = lane >> 5, ec = lane & 31;
  float pb[4][8] = {};
  #pragma unroll 4
  for (int m = 0; m < 32; ++m){
    const short8 xv = *(const short8*)&X[m*256 + ((ec ^ (m & 31)) << 3)];
    const floatx4 pv = *(const floatx4*)&Pl[wid][m][hh*4];
    float xf[8];
    #pragma unroll
    for (int j = 0; j < 8; ++j) xf[j] = bf2f((unsigned short)xv[j]);
    #pragma unroll
    for (int r = 0; r < 4; ++r)
      #pragma unroll
      for (int j = 0; j < 8; ++j) pb[r][j] += pv[r] * xf[j];
  }
  unsigned short* dst = pbar + (size_t)nloc*2048 + ec*8;
  #pragma unroll
  for (int r = 0; r < 4; ++r){
    short8 o;
    #pragma unroll
    for (int j = 0; j < 8; ++j) o[j] = (short)f2bf(pb[r][j]);
    *(short8*)&dst[(hh*4 + r)*256] = o;
  }
}

// ---------------- LayerNorm kernels ----------------
__global__ __launch_bounds__(256) void ln_ff_kernel(const float* __restrict__ a,
    const unsigned short* __restrict__ b, const float* __restrict__ g,
    const float* __restrict__ be, unsigned short* __restrict__ out){
  const int row = blockIdx.x*4 + (threadIdx.x >> 6);
  const int lane = threadIdx.x & 63;
  const size_t base = (size_t)row*ND + lane*4;
  const float4 va = *(const float4*)(a + base);
  const ushort4 vb = *(const ushort4*)(b + base);
  float4 y = { va.x + bf2f(vb.x), va.y + bf2f(vb.y), va.z + bf2f(vb.z), va.w + bf2f(vb.w) };
  float sum = y.x + y.y + y.z + y.w;
  #pragma unroll
  for (int off = 32; off; off >>= 1) sum += __shfl_xor(sum, off, 64);
  const float mu = sum * (1.f/ND);
  float4 d = { y.x-mu, y.y-mu, y.z-mu, y.w-mu };
  float ss = d.x*d.x + d.y*d.y + d.z*d.z + d.w*d.w;
  #pragma unroll
  for (int off = 32; off; off >>= 1) ss += __shfl_xor(ss, off, 64);
  const float rs = rsqrtf(ss * (1.f/ND) + 1e-5f);
  const float4 gv = *(const float4*)(g + lane*4);
  const float4 bv = *(const float4*)(be + lane*4);
  ushort4 o;
  o.x = f2bf(d.x*rs*gv.x + bv.x);
  o.y = f2bf(d.y*rs*gv.y + bv.y);
  o.z = f2bf(d.z*rs*gv.z + bv.z);
  o.w = f2bf(d.w*rs*gv.w + bv.w);
  *(ushort4*)(out + base) = o;
}

__global__ __launch_bounds__(256) void ln_final_kernel(const unsigned short* __restrict__ a,
    const unsigned short* __restrict__ xbp, const float* __restrict__ g,
    const float* __restrict__ be, float* __restrict__ out){
  const int row = blockIdx.x*4 + (threadIdx.x >> 6);
  const int lane = threadIdx.x & 63;
  const size_t base = (size_t)row*ND + lane*4;
  const ushort4 va = *(const ushort4*)(a + base);
  const ushort4 xv = *(const ushort4*)(xbp + base);
  float4 y = { bf2f(va.x) + bf2f(xv.x), bf2f(va.y) + bf2f(xv.y),
               bf2f(va.z) + bf2f(xv.z), bf2f(va.w) + bf2f(xv.w) };
  float sum = y.x + y.y + y.z + y.w;
  #pragma unroll
  for (int off = 32; off; off >>= 1) sum += __shfl_xor(sum, off, 64);
  const float mu = sum * (1.f/ND);
  float4 d = { y.x-mu, y.y-mu, y.z-mu, y.w-mu };
  float ss = d.x*d.x + d.y*d.y + d.z*d.z + d.w*d.w;
  #pragma unroll
  for (int off = 32; off; off >>= 1) ss += __shfl_xor(ss, off, 64);
  const float rs = rsqrtf(ss * (1.f/ND) + 1e-5f);
  const float4 gv = *(const float4*)(g + lane*4);
  const float4 bv = *(const float4*)(be + lane*4);
  float4 o = { d.x*rs*gv.x + bv.x, d.y*rs*gv.y + bv.y, d.z*rs*gv.z + bv.z, d.w*rs*gv.w + bv.w };
  *(float4*)(out + base) = o;
}

// ---------------- launch ----------------
extern "C" void kernel_launch(void* const* d_in, const int* in_sizes, int n_in,
                              void* d_out, int out_size, void* d_ws, size_t ws_size,
                              hipStream_t stream){
  const float* node  = (const float*)d_in[0];
  const float* neigh = (const float*)d_in[1];
  const int*   maskp = (const int*)d_in[2];
  const float* Wq = (const float*)d_in[3];  const float* bq = (const float*)d_in[4];
  const float* Wk = (const float*)d_in[5];  /* bk (d_in[6]) is softmax-invariant -> dropped */
  const float* Wv = (const float*)d_in[7];  const float* bvp = (const float*)d_in[8];
  const float* Wo = (const float*)d_in[9];  const float* bo = (const float*)d_in[10];
  const float* g1 = (const float*)d_in[11]; const float* be1 = (const float*)d_in[12];
  const float* W1 = (const float*)d_in[13]; const float* b1 = (const float*)d_in[14];
  const float* W2 = (const float*)d_in[15]; const float* b2 = (const float*)d_in[16];
  const float* g2 = (const float*)d_in[17]; const float* be2 = (const float*)d_in[18];

  char* ws = (char*)d_ws;
  unsigned short* wq_b  = (unsigned short*)(ws);              // 128K
  unsigned short* w1_b  = (unsigned short*)(ws + 131072);     // 512K
  unsigned short* w2_b  = (unsigned short*)(ws + 655360);     // 512K
  unsigned short* wkt_b = (unsigned short*)(ws + 1179648);    // 128K
  unsigned short* wvo_t = (unsigned short*)(ws + 1310720);    // 1M
  float*          bvo   = (float*)(ws + 2359296);             // 1K
  char* B = ws + 2360320;      // 8M: node_b -> xb
  char* C = B + 8388608;       // 8M: Qb -> t2
  char* D = C + 8388608;       // 8M: t1 ; h spans D+E+F
  char* E = D + 8388608;       // 8M: qk chunk (2048 rows)
  char* F = E + 8388608;       // pbar: 64M/pc

  unsigned short* node_b = (unsigned short*)B;
  unsigned short* xb     = (unsigned short*)B;
  unsigned short* Qb     = (unsigned short*)C;
  unsigned short* t2     = (unsigned short*)C;
  unsigned short* t1     = (unsigned short*)D;
  unsigned short* hbuf   = (unsigned short*)D;   // 32M spans D,E,F
  unsigned short* qkbuf  = (unsigned short*)E;
  unsigned short* pbar   = (unsigned short*)F;

  const size_t baseNeed = 2360320ull + 4ull*8388608ull;  // 35914752
  int pc;
  if      (ws_size >= baseNeed + 67108864ull) pc = 1;
  else if (ws_size >= baseNeed + 33554432ull) pc = 2;
  else if (ws_size >= baseNeed + 16777216ull) pc = 4;   // 52.7MB <= known-available
  else return;
  const int rowsP = NROWS / pc;

  cvt_bf16<<<4096, 256, 0, stream>>>(node, node_b, NROWS*ND/4);
  cvt_bf16<<<64,   256, 0, stream>>>(Wq, wq_b, ND*ND/4);
  cvt_bf16<<<256,  256, 0, stream>>>(W1, w1_b, NFF*ND/4);
  cvt_bf16<<<256,  256, 0, stream>>>(W2, w2_b, NFF*ND/4);
  transpose_cvt<<<64, 256, 0, stream>>>(Wk, wkt_b);
  wvo_kernel<<<2048, 256, 0, stream>>>(Wv, Wo, wvo_t);
  bvo_kernel<<<1, 256, 0, stream>>>(bvp, bo, Wo, bvo);

  // Qb = bf16((node @ Wq^T + bq) / sqrt(32))
  gemm_bt<1><<<dim3(NROWS/128, 2), 256, 0, stream>>>(node_b, wq_b, bq, Qb,
      256, 256, 0.17677669529663687f);

  for (int p = 0; p < pc; ++p){
    for (int s = 0; s < 8/pc; ++s){
      const int n0 = p*rowsP + s*2048;
      gemm_qk<<<dim3(16, 2, 8), 256, 0, stream>>>(Qb + (size_t)n0*256, wkt_b, qkbuf);
      attn2_kernel<<<512, 256, 0, stream>>>(neigh, maskp, qkbuf,
          pbar + (size_t)(n0 - p*rowsP)*2048, n0);
    }
    // t1 chunk = pbar @ Wvo + bvo  -> bf16
    gemm_bt<1><<<dim3(rowsP/128, 2), 256, 0, stream>>>(pbar, wvo_t, bvo,
        t1 + (size_t)p*rowsP*256, 256, 2048, 1.f);
  }

  ln_ff_kernel<<<NROWS/4, 256, 0, stream>>>(node, t1, g1, be1, xb);
  gemm_bt<0><<<dim3(NROWS/128, 8), 256, 0, stream>>>(xb, w1_b, b1, hbuf, 1024, 256, 1.f);
  gemm_bt<1><<<dim3(NROWS/128, 2), 256, 0, stream>>>(hbuf, w2_b, b2, t2, 256, 1024, 1.f);
  ln_final_kernel<<<NROWS/4, 256, 0, stream>>>(t2, xb, g2, be2, (float*)d_out);
}

// Round 4
// 313.634 us; speedup vs baseline: 1.7948x; 1.1952x over previous
//
#include <hip/hip_runtime.h>

#define NM 32
#define ND 256
#define NH 8
#define NFF 1024
#define NROWS 16384

typedef __attribute__((ext_vector_type(8))) short short8;
typedef __attribute__((ext_vector_type(4))) float floatx4;

__device__ __forceinline__ unsigned short f2bf(float f){
  unsigned u = __float_as_uint(f);
  u += 0x7fffu + ((u >> 16) & 1u);
  return (unsigned short)(u >> 16);
}
__device__ __forceinline__ float bf2f(unsigned short s){
  return __uint_as_float(((unsigned)s) << 16);
}

// ---------------- f32 -> bf16 convert ----------------
__global__ __launch_bounds__(256) void cvt_bf16(const float* __restrict__ in,
                                                unsigned short* __restrict__ out, int n4){
  int i = blockIdx.x * 256 + threadIdx.x;
  if (i >= n4) return;
  float4 v = ((const float4*)in)[i];
  ushort4 o;
  o.x = f2bf(v.x); o.y = f2bf(v.y); o.z = f2bf(v.z); o.w = f2bf(v.w);
  ((ushort4*)out)[i] = o;
}

// ---------------- Wk transpose + cvt: Wkt[e][c] = Wk[c][e] (bf16) -------------
__global__ __launch_bounds__(256) void transpose_cvt(const float* __restrict__ in,
    unsigned short* __restrict__ out){
  __shared__ float T[32][33];
  const int ti = blockIdx.x >> 3, tj = blockIdx.x & 7;
  const int tid = threadIdx.x;
  {
    const int r = tid >> 3, c4 = (tid & 7) * 4;
    const float4 v = *(const float4*)&in[(ti*32 + r)*256 + tj*32 + c4];
    T[r][c4+0] = v.x; T[r][c4+1] = v.y; T[r][c4+2] = v.z; T[r][c4+3] = v.w;
  }
  __syncthreads();
  {
    const int cc = tid >> 3, r4 = (tid & 7) * 4;
    ushort4 o;
    o.x = f2bf(T[r4+0][cc]); o.y = f2bf(T[r4+1][cc]);
    o.z = f2bf(T[r4+2][cc]); o.w = f2bf(T[r4+3][cc]);
    *(ushort4*)&out[(tj*32 + cc)*256 + ti*32 + r4] = o;
  }
}

// ---------------- Wvo_t[j][f=(h,e)] = sum_cc Wv[h*32+cc][e] * Wo[j][h*32+cc] ---
__global__ __launch_bounds__(256) void wvo_kernel(const float* __restrict__ Wv,
    const float* __restrict__ Wo, unsigned short* __restrict__ wvo_t){
  __shared__ float WoL[256][33];
  __shared__ float wvv[32];
  const int f = blockIdx.x, h = f >> 8, e = f & 255;
  const int tid = threadIdx.x;
  for (int idx = tid; idx < 8192; idx += 256){
    const int j = idx >> 5, cc = idx & 31;
    WoL[j][cc] = Wo[j*256 + h*32 + cc];
  }
  if (tid < 32) wvv[tid] = Wv[(h*32 + tid)*256 + e];
  __syncthreads();
  float s = 0.f;
  #pragma unroll
  for (int cc = 0; cc < 32; ++cc) s += WoL[tid][cc] * wvv[cc];
  wvo_t[(size_t)tid*2048 + f] = f2bf(s);
}

// ---------------- bvo[j] = bo[j] + sum_c bv[c]*Wo[j][c] ----------------
__global__ __launch_bounds__(256) void bvo_kernel(const float* __restrict__ bv,
    const float* __restrict__ bo, const float* __restrict__ Wo, float* __restrict__ bvo){
  const int j = threadIdx.x;
  float s = bo[j];
  for (int c = 0; c < 256; ++c) s += bv[c] * Wo[j*256 + c];
  bvo[j] = s;
}

// ---------------- GEMM: out = A[.. x K] * W[Nc x K]^T + bias -> bf16 ----------
// EPI 0: relu(acc+bias) -> bf16 ; EPI 1: (acc+bias)*scale -> bf16
template<int EPI>
__global__ __launch_bounds__(256) void gemm_bt(const unsigned short* __restrict__ A,
    const unsigned short* __restrict__ W, const float* __restrict__ bias,
    unsigned short* __restrict__ out, int Nc, int K, float scale){
  __shared__ unsigned short As[128][40];
  __shared__ unsigned short Bs[128][40];
  const int tid = threadIdx.x;
  const int wid = tid >> 6, lane = tid & 63, ln = lane & 15, kh = lane >> 4;
  const int wr = (wid >> 1) * 64, wc = (wid & 1) * 64;
  const int row0 = blockIdx.x * 128, col0 = blockIdx.y * 128;
  const int lr = tid >> 2, lc = (tid & 3) * 8;
  floatx4 acc[4][4] = {};
  for (int k0 = 0; k0 < K; k0 += 32){
    __syncthreads();
    *(short8*)&As[lr][lc]    = *(const short8*)&A[(size_t)(row0+lr)*K + k0 + lc];
    *(short8*)&As[lr+64][lc] = *(const short8*)&A[(size_t)(row0+lr+64)*K + k0 + lc];
    *(short8*)&Bs[lr][lc]    = *(const short8*)&W[(size_t)(col0+lr)*K + k0 + lc];
    *(short8*)&Bs[lr+64][lc] = *(const short8*)&W[(size_t)(col0+lr+64)*K + k0 + lc];
    __syncthreads();
    short8 af[4], bf[4];
    #pragma unroll
    for (int t = 0; t < 4; ++t) af[t] = *(const short8*)&As[wr + t*16 + ln][kh*8];
    #pragma unroll
    for (int t = 0; t < 4; ++t) bf[t] = *(const short8*)&Bs[wc + t*16 + ln][kh*8];
    #pragma unroll
    for (int mt = 0; mt < 4; ++mt)
      #pragma unroll
      for (int nt = 0; nt < 4; ++nt)
        acc[mt][nt] = __builtin_amdgcn_mfma_f32_16x16x32_bf16(af[mt], bf[nt], acc[mt][nt], 0, 0, 0);
  }
  #pragma unroll
  for (int mt = 0; mt < 4; ++mt){
    #pragma unroll
    for (int nt = 0; nt < 4; ++nt){
      const int gc = col0 + wc + nt*16 + ln;
      const float bs = bias[gc];
      #pragma unroll
      for (int r = 0; r < 4; ++r){
        const int gr = row0 + wr + mt*16 + kh*4 + r;
        float v = acc[mt][nt][r] + bs;
        if (EPI == 0) out[(size_t)gr*Nc + gc] = f2bf(fmaxf(v, 0.f));
        else          out[(size_t)gr*Nc + gc] = f2bf(v * scale);
      }
    }
  }
}

// ---------------- split-K GEMM: out[z] = A @ W^T over K-half z, f32, no bias ---
__global__ __launch_bounds__(256) void gemm_ks(const unsigned short* __restrict__ A,
    const unsigned short* __restrict__ W, float* __restrict__ out,
    int Nc, int K, int Khalf){
  __shared__ unsigned short As[128][40];
  __shared__ unsigned short Bs[128][40];
  const int tid = threadIdx.x;
  const int wid = tid >> 6, lane = tid & 63, ln = lane & 15, kh = lane >> 4;
  const int wr = (wid >> 1) * 64, wc = (wid & 1) * 64;
  const int row0 = blockIdx.x * 128, col0 = blockIdx.y * 128;
  const int kb = blockIdx.z * Khalf;
  const int lr = tid >> 2, lc = (tid & 3) * 8;
  float* op = out + (size_t)blockIdx.z * NROWS * Nc;
  floatx4 acc[4][4] = {};
  for (int k0 = kb; k0 < kb + Khalf; k0 += 32){
    __syncthreads();
    *(short8*)&As[lr][lc]    = *(const short8*)&A[(size_t)(row0+lr)*K + k0 + lc];
    *(short8*)&As[lr+64][lc] = *(const short8*)&A[(size_t)(row0+lr+64)*K + k0 + lc];
    *(short8*)&Bs[lr][lc]    = *(const short8*)&W[(size_t)(col0+lr)*K + k0 + lc];
    *(short8*)&Bs[lr+64][lc] = *(const short8*)&W[(size_t)(col0+lr+64)*K + k0 + lc];
    __syncthreads();
    short8 af[4], bf[4];
    #pragma unroll
    for (int t = 0; t < 4; ++t) af[t] = *(const short8*)&As[wr + t*16 + ln][kh*8];
    #pragma unroll
    for (int t = 0; t < 4; ++t) bf[t] = *(const short8*)&Bs[wc + t*16 + ln][kh*8];
    #pragma unroll
    for (int mt = 0; mt < 4; ++mt)
      #pragma unroll
      for (int nt = 0; nt < 4; ++nt)
        acc[mt][nt] = __builtin_amdgcn_mfma_f32_16x16x32_bf16(af[mt], bf[nt], acc[mt][nt], 0, 0, 0);
  }
  #pragma unroll
  for (int mt = 0; mt < 4; ++mt)
    #pragma unroll
    for (int nt = 0; nt < 4; ++nt){
      const int gc = col0 + wc + nt*16 + ln;
      #pragma unroll
      for (int r = 0; r < 4; ++r)
        op[(size_t)(row0 + wr + mt*16 + kh*4 + r)*Nc + gc] = acc[mt][nt][r];
    }
}

// ---------------- qk GEMM (per head, K=32): qk[n][h*256+e] -------------------
__global__ __launch_bounds__(256) void gemm_qk(const unsigned short* __restrict__ A,
    const unsigned short* __restrict__ Wkt, unsigned short* __restrict__ out){
  __shared__ unsigned short As[128][40];
  __shared__ unsigned short Bs[128][40];
  const int tid = threadIdx.x;
  const int wid = tid >> 6, lane = tid & 63, ln = lane & 15, kh = lane >> 4;
  const int wr = (wid >> 1) * 64, wc = (wid & 1) * 64;
  const int row0 = blockIdx.x * 128, col0 = blockIdx.y * 128, h = blockIdx.z;
  #pragma unroll
  for (int it = 0; it < 2; ++it){
    const int flat = it*256 + tid;
    const int r = flat >> 2, c = flat & 3;
    *(short8*)&As[r][c*8] = *(const short8*)&A[(size_t)(row0+r)*256 + h*32 + c*8];
    *(short8*)&Bs[r][c*8] = *(const short8*)&Wkt[(size_t)(col0+r)*256 + h*32 + c*8];
  }
  __syncthreads();
  short8 af[4], bf[4];
  #pragma unroll
  for (int t = 0; t < 4; ++t) af[t] = *(const short8*)&As[wr + t*16 + ln][kh*8];
  #pragma unroll
  for (int t = 0; t < 4; ++t) bf[t] = *(const short8*)&Bs[wc + t*16 + ln][kh*8];
  floatx4 acc[4][4] = {};
  #pragma unroll
  for (int mt = 0; mt < 4; ++mt)
    #pragma unroll
    for (int nt = 0; nt < 4; ++nt)
      acc[mt][nt] = __builtin_amdgcn_mfma_f32_16x16x32_bf16(af[mt], bf[nt], acc[mt][nt], 0, 0, 0);
  #pragma unroll
  for (int mt = 0; mt < 4; ++mt)
    #pragma unroll
    for (int nt = 0; nt < 4; ++nt)
      #pragma unroll
      for (int r = 0; r < 4; ++r)
        out[(size_t)(row0 + wr + mt*16 + kh*4 + r)*2048 + h*256 + col0 + wc + nt*16 + ln]
            = f2bf(acc[mt][nt][r]);
}

// ---------------- fused attention: 1 wave = 1 node, no barriers ----------------
__global__ __launch_bounds__(256) void attn2_kernel(const float* __restrict__ neigh,
    const int* __restrict__ mask, const unsigned short* __restrict__ qk,
    unsigned short* __restrict__ pbar){
  __shared__ unsigned short Xs[4][8192];   // XOR-swizzled 16B slots
  __shared__ float Pl[4][32][8];
  __shared__ float Mf[4][32];
  const int tid = threadIdx.x;
  const int wid = tid >> 6, lane = tid & 63;
  const int ln = lane & 15, kh = lane >> 4;
  const size_t nid = (size_t)blockIdx.x * 4 + wid;
  unsigned short* X = Xs[wid];

  // qk B-fragments from global, issued early (latency hides under staging)
  short8 bfrag[8];
  const unsigned short* qkn = qk + nid*2048 + (size_t)(ln & 7)*256;
  #pragma unroll
  for (int kk = 0; kk < 8; ++kk) bfrag[kk] = *(const short8*)&qkn[kk*32 + kh*8];

  if (lane < 32) Mf[wid][lane] = mask[nid*NM + lane] ? 0.f : -1e9f;

  // stage X (32x256 f32 -> bf16, swizzled)
  const float* xg = neigh + nid * (NM*ND);
  #pragma unroll
  for (int i = 0; i < 16; ++i){
    const int flat8 = i*64 + lane;
    const int m = flat8 >> 5, ec = flat8 & 31;
    const float4 a = *(const float4*)&xg[flat8*8];
    const float4 b = *(const float4*)&xg[flat8*8 + 4];
    short8 v;
    v[0]=(short)f2bf(a.x); v[1]=(short)f2bf(a.y); v[2]=(short)f2bf(a.z); v[3]=(short)f2bf(a.w);
    v[4]=(short)f2bf(b.x); v[5]=(short)f2bf(b.y); v[6]=(short)f2bf(b.z); v[7]=(short)f2bf(b.w);
    *(short8*)&X[m*256 + ((ec ^ (m & 31)) << 3)] = v;
  }

  // scores [32m x 16h] = X @ qk^T (cols 8..15 duplicate 0..7, ignored)
  floatx4 acc0 = {}, acc1 = {};
  #pragma unroll
  for (int kk = 0; kk < 8; ++kk){
    const int slot = kk*4 + kh;
    const int m0 = ln, m1 = 16 + ln;
    const short8 a0 = *(const short8*)&X[m0*256 + ((slot ^ (m0 & 31)) << 3)];
    const short8 a1 = *(const short8*)&X[m1*256 + ((slot ^ (m1 & 31)) << 3)];
    acc0 = __builtin_amdgcn_mfma_f32_16x16x32_bf16(a0, bfrag[kk], acc0, 0, 0, 0);
    acc1 = __builtin_amdgcn_mfma_f32_16x16x32_bf16(a1, bfrag[kk], acc1, 0, 0, 0);
  }

  // softmax over m per head h=ln; rows on lanes {ln, ln+16, ln+32, ln+48}
  float p8[8]; float mx = -3.0e38f;
  #pragma unroll
  for (int r = 0; r < 4; ++r){
    const float s0 = acc0[r] + Mf[wid][kh*4 + r];
    const float s1 = acc1[r] + Mf[wid][16 + kh*4 + r];
    p8[r] = s0; p8[4+r] = s1;
    mx = fmaxf(mx, fmaxf(s0, s1));
  }
  mx = fmaxf(mx, __shfl_xor(mx, 16));
  mx = fmaxf(mx, __shfl_xor(mx, 32));
  float sum = 0.f;
  #pragma unroll
  for (int k = 0; k < 8; ++k){ p8[k] = __expf(p8[k] - mx); sum += p8[k]; }
  sum += __shfl_xor(sum, 16);
  sum += __shfl_xor(sum, 32);
  const float inv = 1.f / sum;
  if (ln < 8){
    #pragma unroll
    for (int r = 0; r < 4; ++r){
      Pl[wid][kh*4 + r][ln]      = p8[r]   * inv;
      Pl[wid][16 + kh*4 + r][ln] = p8[4+r] * inv;
    }
  }

  // Pbar[h][e] = sum_m P[h][m] * X[m][e]; lane = (hh, ec): 4 heads x 8 elems
  const int hh = lane >> 5, ec = lane & 31;
  float pb[4][8] = {};
  #pragma unroll 4
  for (int m = 0; m < 32; ++m){
    const short8 xv = *(const short8*)&X[m*256 + ((ec ^ (m & 31)) << 3)];
    const floatx4 pv = *(const floatx4*)&Pl[wid][m][hh*4];
    float xf[8];
    #pragma unroll
    for (int j = 0; j < 8; ++j) xf[j] = bf2f((unsigned short)xv[j]);
    #pragma unroll
    for (int r = 0; r < 4; ++r)
      #pragma unroll
      for (int j = 0; j < 8; ++j) pb[r][j] += pv[r] * xf[j];
  }
  unsigned short* dst = pbar + nid*2048 + ec*8;
  #pragma unroll
  for (int r = 0; r < 4; ++r){
    short8 o;
    #pragma unroll
    for (int j = 0; j < 8; ++j) o[j] = (short)f2bf(pb[r][j]);
    *(short8*)&dst[(hh*4 + r)*256] = o;
  }
}

// ---------------- LN1: xb = LN(node + t1a + t1b + bvo) -> bf16 ----------------
__global__ __launch_bounds__(256) void ln_ff_kernel(const float* __restrict__ a,
    const float* __restrict__ p1, const float* __restrict__ p2,
    const float* __restrict__ bvo, const float* __restrict__ g,
    const float* __restrict__ be, unsigned short* __restrict__ out){
  const int row = blockIdx.x*4 + (threadIdx.x >> 6);
  const int lane = threadIdx.x & 63;
  const size_t base = (size_t)row*ND + lane*4;
  const float4 va = *(const float4*)(a + base);
  const float4 v1 = *(const float4*)(p1 + base);
  const float4 v2 = *(const float4*)(p2 + base);
  const float4 vb = *(const float4*)(bvo + lane*4);
  float4 y = { va.x+v1.x+v2.x+vb.x, va.y+v1.y+v2.y+vb.y,
               va.z+v1.z+v2.z+vb.z, va.w+v1.w+v2.w+vb.w };
  float sum = y.x + y.y + y.z + y.w;
  #pragma unroll
  for (int off = 32; off; off >>= 1) sum += __shfl_xor(sum, off, 64);
  const float mu = sum * (1.f/ND);
  float4 d = { y.x-mu, y.y-mu, y.z-mu, y.w-mu };
  float ss = d.x*d.x + d.y*d.y + d.z*d.z + d.w*d.w;
  #pragma unroll
  for (int off = 32; off; off >>= 1) ss += __shfl_xor(ss, off, 64);
  const float rs = rsqrtf(ss * (1.f/ND) + 1e-5f);
  const float4 gv = *(const float4*)(g + lane*4);
  const float4 bv = *(const float4*)(be + lane*4);
  ushort4 o;
  o.x = f2bf(d.x*rs*gv.x + bv.x);
  o.y = f2bf(d.y*rs*gv.y + bv.y);
  o.z = f2bf(d.z*rs*gv.z + bv.z);
  o.w = f2bf(d.w*rs*gv.w + bv.w);
  *(ushort4*)(out + base) = o;
}

// ---------------- LN2: out = LN(xb + t2a + t2b + b2) -> f32 ----------------
__global__ __launch_bounds__(256) void ln_final_kernel(const unsigned short* __restrict__ xbp,
    const float* __restrict__ p1, const float* __restrict__ p2,
    const float* __restrict__ b2, const float* __restrict__ g,
    const float* __restrict__ be, float* __restrict__ out){
  const int row = blockIdx.x*4 + (threadIdx.x >> 6);
  const int lane = threadIdx.x & 63;
  const size_t base = (size_t)row*ND + lane*4;
  const ushort4 xv = *(const ushort4*)(xbp + base);
  const float4 v1 = *(const float4*)(p1 + base);
  const float4 v2 = *(const float4*)(p2 + base);
  const float4 vb = *(const float4*)(b2 + lane*4);
  float4 y = { bf2f(xv.x)+v1.x+v2.x+vb.x, bf2f(xv.y)+v1.y+v2.y+vb.y,
               bf2f(xv.z)+v1.z+v2.z+vb.z, bf2f(xv.w)+v1.w+v2.w+vb.w };
  float sum = y.x + y.y + y.z + y.w;
  #pragma unroll
  for (int off = 32; off; off >>= 1) sum += __shfl_xor(sum, off, 64);
  const float mu = sum * (1.f/ND);
  float4 d = { y.x-mu, y.y-mu, y.z-mu, y.w-mu };
  float ss = d.x*d.x + d.y*d.y + d.z*d.z + d.w*d.w;
  #pragma unroll
  for (int off = 32; off; off >>= 1) ss += __shfl_xor(ss, off, 64);
  const float rs = rsqrtf(ss * (1.f/ND) + 1e-5f);
  const float4 gv = *(const float4*)(g + lane*4);
  const float4 bv = *(const float4*)(be + lane*4);
  float4 o = { d.x*rs*gv.x + bv.x, d.y*rs*gv.y + bv.y, d.z*rs*gv.z + bv.z, d.w*rs*gv.w + bv.w };
  *(float4*)(out + base) = o;
}

// ---------------- launch ----------------
extern "C" void kernel_launch(void* const* d_in, const int* in_sizes, int n_in,
                              void* d_out, int out_size, void* d_ws, size_t ws_size,
                              hipStream_t stream){
  const float* node  = (const float*)d_in[0];
  const float* neigh = (const float*)d_in[1];
  const int*   maskp = (const int*)d_in[2];
  const float* Wq = (const float*)d_in[3];  const float* bq = (const float*)d_in[4];
  const float* Wk = (const float*)d_in[5];  /* bk dropped: softmax-invariant */
  const float* Wv = (const float*)d_in[7];  const float* bvp = (const float*)d_in[8];
  const float* Wo = (const float*)d_in[9];  const float* bo = (const float*)d_in[10];
  const float* g1 = (const float*)d_in[11]; const float* be1 = (const float*)d_in[12];
  const float* W1 = (const float*)d_in[13]; const float* b1 = (const float*)d_in[14];
  const float* W2 = (const float*)d_in[15]; const float* b2 = (const float*)d_in[16];
  const float* g2 = (const float*)d_in[17]; const float* be2 = (const float*)d_in[18];

  char* ws = (char*)d_ws;
  unsigned short* wq_b  = (unsigned short*)(ws);              // 128K
  unsigned short* w1_b  = (unsigned short*)(ws + 131072);     // 512K
  unsigned short* w2_b  = (unsigned short*)(ws + 655360);     // 512K
  unsigned short* wkt_b = (unsigned short*)(ws + 1179648);    // 128K
  unsigned short* wvo_t = (unsigned short*)(ws + 1310720);    // 1M
  float*          bvo   = (float*)(ws + 2359296);             // 1K

  const size_t MB = 1048576ull;
  char* big = ws + 4*MB;
  unsigned short* node_b = (unsigned short*)(big);            // 8M
  unsigned short* Qb     = (unsigned short*)(big + 8*MB);     // 8M
  unsigned short* xb     = (unsigned short*)(big + 16*MB);    // 8M
  unsigned short* qk     = (unsigned short*)(big + 24*MB);    // 64M
  unsigned short* pbar   = (unsigned short*)(big + 88*MB);    // 64M
  float*          t1a    = (float*)(big + 152*MB);            // 16M (t1b follows)
  unsigned short* hbuf   = (unsigned short*)(big + 184*MB);   // 32M
  float*          t2a    = (float*)(big + 216*MB);            // 16M (t2b follows)
  const size_t need = 4*MB + 248*MB;
  if (ws_size < need) return;   // ws proven ~2GiB (fillBuffer WRITE_SIZE), guard anyway

  cvt_bf16<<<4096, 256, 0, stream>>>(node, node_b, NROWS*ND/4);
  cvt_bf16<<<64,   256, 0, stream>>>(Wq, wq_b, ND*ND/4);
  cvt_bf16<<<256,  256, 0, stream>>>(W1, w1_b, NFF*ND/4);
  cvt_bf16<<<256,  256, 0, stream>>>(W2, w2_b, NFF*ND/4);
  transpose_cvt<<<64, 256, 0, stream>>>(Wk, wkt_b);
  wvo_kernel<<<2048, 256, 0, stream>>>(Wv, Wo, wvo_t);
  bvo_kernel<<<1, 256, 0, stream>>>(bvp, bo, Wo, bvo);

  // Qb = bf16((node @ Wq^T + bq) / sqrt(32))
  gemm_bt<1><<<dim3(NROWS/128, 2), 256, 0, stream>>>(node_b, wq_b, bq, Qb,
      256, 256, 0.17677669529663687f);
  // qk[n][h*256+e] for all rows (one dispatch)
  gemm_qk<<<dim3(NROWS/128, 2, 8), 256, 0, stream>>>(Qb, wkt_b, qk);
  // fused attention for all rows (one dispatch)
  attn2_kernel<<<NROWS/4, 256, 0, stream>>>(neigh, maskp, qk, pbar);
  // t1 = pbar @ Wvo (split-K=2, f32 partials; bias folded into LN1)
  gemm_ks<<<dim3(NROWS/128, 2, 2), 256, 0, stream>>>(pbar, wvo_t, t1a, 256, 2048, 1024);
  // xb = LN1(node + t1a + t1b + bvo)
  ln_ff_kernel<<<NROWS/4, 256, 0, stream>>>(node, t1a, t1a + (size_t)NROWS*256,
      bvo, g1, be1, xb);
  // h = relu(xb @ W1^T + b1)
  gemm_bt<0><<<dim3(NROWS/128, 8), 256, 0, stream>>>(xb, w1_b, b1, hbuf, 1024, 256, 1.f);
  // t2 = h @ W2^T (split-K=2, f32 partials; bias folded into LN2)
  gemm_ks<<<dim3(NROWS/128, 2, 2), 256, 0, stream>>>(hbuf, w2_b, t2a, 256, 1024, 512);
  // out = LN2(xb + t2a + t2b + b2)
  ln_final_kernel<<<NROWS/4, 256, 0, stream>>>(xb, t2a, t2a + (size_t)NROWS*256,
      b2, g2, be2, (float*)d_out);
}

// Round 5
// 308.015 us; speedup vs baseline: 1.8275x; 1.0182x over previous
//
#include <hip/hip_runtime.h>

#define NM 32
#define ND 256
#define NH 8
#define NFF 1024
#define NROWS 16384

typedef __attribute__((ext_vector_type(8))) short short8;
typedef __attribute__((ext_vector_type(4))) float floatx4;

__device__ __forceinline__ unsigned short f2bf(float f){
  unsigned u = __float_as_uint(f);
  u += 0x7fffu + ((u >> 16) & 1u);
  return (unsigned short)(u >> 16);
}
__device__ __forceinline__ float bf2f(unsigned short s){
  return __uint_as_float(((unsigned)s) << 16);
}

// ================= mega-prep: all weight conversions in ONE dispatch =========
// blocks [0,4096): node f32->bf16          [4096,4160): Wq cvt
// [4160,4416): W1 cvt                      [4416,4672): W2 cvt
// [4672,4736): Wk transpose+cvt            [4736,6784): Wvo fold
// [6784]: bvo fold
__global__ __launch_bounds__(256) void prep_kernel(
    const float* __restrict__ node, unsigned short* __restrict__ node_b,
    const float* __restrict__ Wq, unsigned short* __restrict__ wq_b,
    const float* __restrict__ W1, unsigned short* __restrict__ w1_b,
    const float* __restrict__ W2, unsigned short* __restrict__ w2_b,
    const float* __restrict__ Wk, unsigned short* __restrict__ wkt_b,
    const float* __restrict__ Wv, const float* __restrict__ Wo,
    unsigned short* __restrict__ wvo_t,
    const float* __restrict__ bv, const float* __restrict__ bo,
    float* __restrict__ bvo){
  __shared__ float smem[256*33 + 32];
  const int b = blockIdx.x, tid = threadIdx.x;
  if (b < 4672){
    const float* src; unsigned short* dst; int i;
    if      (b < 4096){ src = node; dst = node_b; i = b*256 + tid; }
    else if (b < 4160){ src = Wq;   dst = wq_b;   i = (b-4096)*256 + tid; }
    else if (b < 4416){ src = W1;   dst = w1_b;   i = (b-4160)*256 + tid; }
    else              { src = W2;   dst = w2_b;   i = (b-4416)*256 + tid; }
    const float4 v = ((const float4*)src)[i];
    ushort4 o; o.x=f2bf(v.x); o.y=f2bf(v.y); o.z=f2bf(v.z); o.w=f2bf(v.w);
    ((ushort4*)dst)[i] = o;
  } else if (b < 4736){
    float (*T)[33] = (float(*)[33])smem;
    const int bb = b - 4672, ti = bb >> 3, tj = bb & 7;
    {
      const int r = tid >> 3, c4 = (tid & 7) * 4;
      const float4 v = *(const float4*)&Wk[(ti*32 + r)*256 + tj*32 + c4];
      T[r][c4+0]=v.x; T[r][c4+1]=v.y; T[r][c4+2]=v.z; T[r][c4+3]=v.w;
    }
    __syncthreads();
    {
      const int cc = tid >> 3, r4 = (tid & 7) * 4;
      ushort4 o;
      o.x=f2bf(T[r4+0][cc]); o.y=f2bf(T[r4+1][cc]);
      o.z=f2bf(T[r4+2][cc]); o.w=f2bf(T[r4+3][cc]);
      *(ushort4*)&wkt_b[(tj*32 + cc)*256 + ti*32 + r4] = o;
    }
  } else if (b < 6784){
    float (*WoL)[33] = (float(*)[33])smem;
    float* wvv = smem + 256*33;
    const int f = b - 4736, h = f >> 8, e = f & 255;
    for (int idx = tid; idx < 8192; idx += 256){
      const int j = idx >> 5, cc = idx & 31;
      WoL[j][cc] = Wo[j*256 + h*32 + cc];
    }
    if (tid < 32) wvv[tid] = Wv[(h*32 + tid)*256 + e];
    __syncthreads();
    float s = 0.f;
    #pragma unroll
    for (int cc = 0; cc < 32; ++cc) s += WoL[tid][cc] * wvv[cc];
    wvo_t[(size_t)tid*2048 + f] = f2bf(s);
  } else {
    const int j = tid;
    float s = bo[j];
    for (int c = 0; c < 256; ++c) s += bv[c] * Wo[j*256 + c];
    bvo[j] = s;
  }
}

// ================ gemm64: 64x128 tile, 4 waves (2x2 of 32x64) ===============
// EPI 0: relu(acc+bias)->bf16 ; EPI 1: (acc+bias)*scale->bf16 ; EPI 2: acc+bias->f32
template<int EPI>
__global__ __launch_bounds__(256) void gemm64(const unsigned short* __restrict__ A,
    const unsigned short* __restrict__ W, const float* __restrict__ bias,
    void* __restrict__ out, int Nc, int K, float scale){
  __shared__ unsigned short As[64][40];
  __shared__ unsigned short Bs[128][40];
  const int tid = threadIdx.x;
  const int wid = tid >> 6, lane = tid & 63, ln = lane & 15, kh = lane >> 4;
  const int wr = (wid >> 1) * 32, wc = (wid & 1) * 64;
  const int row0 = blockIdx.x * 64, col0 = blockIdx.y * 128;
  const int ar = tid >> 2, ac = (tid & 3) * 8;
  const int br = tid >> 1, bc = (tid & 1) * 16;
  floatx4 acc[2][4] = {};
  for (int k0 = 0; k0 < K; k0 += 32){
    __syncthreads();
    *(short8*)&As[ar][ac]   = *(const short8*)&A[(size_t)(row0+ar)*K + k0 + ac];
    *(short8*)&Bs[br][bc]   = *(const short8*)&W[(size_t)(col0+br)*K + k0 + bc];
    *(short8*)&Bs[br][bc+8] = *(const short8*)&W[(size_t)(col0+br)*K + k0 + bc + 8];
    __syncthreads();
    short8 af[2], bf[4];
    #pragma unroll
    for (int t = 0; t < 2; ++t) af[t] = *(const short8*)&As[wr + t*16 + ln][kh*8];
    #pragma unroll
    for (int t = 0; t < 4; ++t) bf[t] = *(const short8*)&Bs[wc + t*16 + ln][kh*8];
    #pragma unroll
    for (int mt = 0; mt < 2; ++mt)
      #pragma unroll
      for (int nt = 0; nt < 4; ++nt)
        acc[mt][nt] = __builtin_amdgcn_mfma_f32_16x16x32_bf16(af[mt], bf[nt], acc[mt][nt], 0, 0, 0);
  }
  #pragma unroll
  for (int mt = 0; mt < 2; ++mt){
    #pragma unroll
    for (int nt = 0; nt < 4; ++nt){
      const int gc = col0 + wc + nt*16 + ln;
      const float bs = bias[gc];
      #pragma unroll
      for (int r = 0; r < 4; ++r){
        const int gr = row0 + wr + mt*16 + kh*4 + r;
        const float v = acc[mt][nt][r] + bs;
        if      (EPI == 0) ((unsigned short*)out)[(size_t)gr*Nc + gc] = f2bf(fmaxf(v, 0.f));
        else if (EPI == 1) ((unsigned short*)out)[(size_t)gr*Nc + gc] = f2bf(v * scale);
        else               ((float*)out)[(size_t)gr*Nc + gc] = v;
      }
    }
  }
}

// ---------------- qk GEMM (per head, K=32): qk[n][h*256+e] -------------------
__global__ __launch_bounds__(256) void gemm_qk(const unsigned short* __restrict__ A,
    const unsigned short* __restrict__ Wkt, unsigned short* __restrict__ out){
  __shared__ unsigned short As[128][40];
  __shared__ unsigned short Bs[128][40];
  const int tid = threadIdx.x;
  const int wid = tid >> 6, lane = tid & 63, ln = lane & 15, kh = lane >> 4;
  const int wr = (wid >> 1) * 64, wc = (wid & 1) * 64;
  const int row0 = blockIdx.x * 128, col0 = blockIdx.y * 128, h = blockIdx.z;
  #pragma unroll
  for (int it = 0; it < 2; ++it){
    const int flat = it*256 + tid;
    const int r = flat >> 2, c = flat & 3;
    *(short8*)&As[r][c*8] = *(const short8*)&A[(size_t)(row0+r)*256 + h*32 + c*8];
    *(short8*)&Bs[r][c*8] = *(const short8*)&Wkt[(size_t)(col0+r)*256 + h*32 + c*8];
  }
  __syncthreads();
  short8 af[4], bf[4];
  #pragma unroll
  for (int t = 0; t < 4; ++t) af[t] = *(const short8*)&As[wr + t*16 + ln][kh*8];
  #pragma unroll
  for (int t = 0; t < 4; ++t) bf[t] = *(const short8*)&Bs[wc + t*16 + ln][kh*8];
  floatx4 acc[4][4] = {};
  #pragma unroll
  for (int mt = 0; mt < 4; ++mt)
    #pragma unroll
    for (int nt = 0; nt < 4; ++nt)
      acc[mt][nt] = __builtin_amdgcn_mfma_f32_16x16x32_bf16(af[mt], bf[nt], acc[mt][nt], 0, 0, 0);
  #pragma unroll
  for (int mt = 0; mt < 4; ++mt)
    #pragma unroll
    for (int nt = 0; nt < 4; ++nt)
      #pragma unroll
      for (int r = 0; r < 4; ++r)
        out[(size_t)(row0 + wr + mt*16 + kh*4 + r)*2048 + h*256 + col0 + wc + nt*16 + ln]
            = f2bf(acc[mt][nt][r]);
}

// ---------------- fused attention: 1 wave = 1 node, no barriers ----------------
__global__ __launch_bounds__(256) void attn2_kernel(const float* __restrict__ neigh,
    const int* __restrict__ mask, const unsigned short* __restrict__ qk,
    unsigned short* __restrict__ pbar){
  __shared__ unsigned short Xs[4][8192];   // XOR-swizzled 16B slots
  __shared__ float Pl[4][32][8];
  __shared__ float Mf[4][32];
  const int tid = threadIdx.x;
  const int wid = tid >> 6, lane = tid & 63;
  const int ln = lane & 15, kh = lane >> 4;
  const size_t nid = (size_t)blockIdx.x * 4 + wid;
  unsigned short* X = Xs[wid];

  // mask first (tiny load, drains during staging)
  int mk = 0;
  if (lane < 32) mk = mask[nid*NM + lane];

  // burst-issue ALL staging loads (32 x 16B per lane in flight)
  const float* xg = neigh + nid * (NM*ND);
  float4 va[16], vb[16];
  #pragma unroll
  for (int i = 0; i < 16; ++i){
    const int f8 = i*64 + lane;
    va[i] = *(const float4*)&xg[f8*8];
    vb[i] = *(const float4*)&xg[f8*8 + 4];
  }
  // qk B-fragments issued behind the staging burst
  short8 bfrag[8];
  const unsigned short* qkn = qk + nid*2048 + (size_t)(ln & 7)*256;
  #pragma unroll
  for (int kk = 0; kk < 8; ++kk) bfrag[kk] = *(const short8*)&qkn[kk*32 + kh*8];

  if (lane < 32) Mf[wid][lane] = mk ? 0.f : -1e9f;

  // convert + swizzled LDS write
  #pragma unroll
  for (int i = 0; i < 16; ++i){
    const int f8 = i*64 + lane;
    const int m = f8 >> 5, ec = f8 & 31;
    short8 v;
    v[0]=(short)f2bf(va[i].x); v[1]=(short)f2bf(va[i].y);
    v[2]=(short)f2bf(va[i].z); v[3]=(short)f2bf(va[i].w);
    v[4]=(short)f2bf(vb[i].x); v[5]=(short)f2bf(vb[i].y);
    v[6]=(short)f2bf(vb[i].z); v[7]=(short)f2bf(vb[i].w);
    *(short8*)&X[m*256 + ((ec ^ (m & 31)) << 3)] = v;
  }

  // scores [32m x 16h] = X @ qk^T (cols 8..15 duplicate 0..7, ignored)
  floatx4 acc0 = {}, acc1 = {};
  #pragma unroll
  for (int kk = 0; kk < 8; ++kk){
    const int slot = kk*4 + kh;
    const int m0 = ln, m1 = 16 + ln;
    const short8 a0 = *(const short8*)&X[m0*256 + ((slot ^ (m0 & 31)) << 3)];
    const short8 a1 = *(const short8*)&X[m1*256 + ((slot ^ (m1 & 31)) << 3)];
    acc0 = __builtin_amdgcn_mfma_f32_16x16x32_bf16(a0, bfrag[kk], acc0, 0, 0, 0);
    acc1 = __builtin_amdgcn_mfma_f32_16x16x32_bf16(a1, bfrag[kk], acc1, 0, 0, 0);
  }

  // softmax over m per head h=ln; rows on lanes {ln, ln+16, ln+32, ln+48}
  float p8[8]; float mx = -3.0e38f;
  #pragma unroll
  for (int r = 0; r < 4; ++r){
    const float s0 = acc0[r] + Mf[wid][kh*4 + r];
    const float s1 = acc1[r] + Mf[wid][16 + kh*4 + r];
    p8[r] = s0; p8[4+r] = s1;
    mx = fmaxf(mx, fmaxf(s0, s1));
  }
  mx = fmaxf(mx, __shfl_xor(mx, 16));
  mx = fmaxf(mx, __shfl_xor(mx, 32));
  float sum = 0.f;
  #pragma unroll
  for (int k = 0; k < 8; ++k){ p8[k] = __expf(p8[k] - mx); sum += p8[k]; }
  sum += __shfl_xor(sum, 16);
  sum += __shfl_xor(sum, 32);
  const float inv = 1.f / sum;
  if (ln < 8){
    #pragma unroll
    for (int r = 0; r < 4; ++r){
      Pl[wid][kh*4 + r][ln]      = p8[r]   * inv;
      Pl[wid][16 + kh*4 + r][ln] = p8[4+r] * inv;
    }
  }

  // Pbar[h][e] = sum_m P[h][m] * X[m][e]; lane = (hh, ec): 4 heads x 8 elems
  const int hh = lane >> 5, ec = lane & 31;
  float pb[4][8] = {};
  #pragma unroll 4
  for (int m = 0; m < 32; ++m){
    const short8 xv = *(const short8*)&X[m*256 + ((ec ^ (m & 31)) << 3)];
    const floatx4 pv = *(const floatx4*)&Pl[wid][m][hh*4];
    float xf[8];
    #pragma unroll
    for (int j = 0; j < 8; ++j) xf[j] = bf2f((unsigned short)xv[j]);
    #pragma unroll
    for (int r = 0; r < 4; ++r)
      #pragma unroll
      for (int j = 0; j < 8; ++j) pb[r][j] += pv[r] * xf[j];
  }
  unsigned short* dst = pbar + nid*2048 + ec*8;
  #pragma unroll
  for (int r = 0; r < 4; ++r){
    short8 o;
    #pragma unroll
    for (int j = 0; j < 8; ++j) o[j] = (short)f2bf(pb[r][j]);
    *(short8*)&dst[(hh*4 + r)*256] = o;
  }
}

// ---------------- LN1: xb = LN(node + t1) -> bf16 (t1 has bvo folded) --------
__global__ __launch_bounds__(256) void ln_ff_kernel(const float* __restrict__ a,
    const float* __restrict__ t1, const float* __restrict__ g,
    const float* __restrict__ be, unsigned short* __restrict__ out){
  const int row = blockIdx.x*4 + (threadIdx.x >> 6);
  const int lane = threadIdx.x & 63;
  const size_t base = (size_t)row*ND + lane*4;
  const float4 va = *(const float4*)(a + base);
  const float4 v1 = *(const float4*)(t1 + base);
  float4 y = { va.x+v1.x, va.y+v1.y, va.z+v1.z, va.w+v1.w };
  float sum = y.x + y.y + y.z + y.w;
  #pragma unroll
  for (int off = 32; off; off >>= 1) sum += __shfl_xor(sum, off, 64);
  const float mu = sum * (1.f/ND);
  float4 d = { y.x-mu, y.y-mu, y.z-mu, y.w-mu };
  float ss = d.x*d.x + d.y*d.y + d.z*d.z + d.w*d.w;
  #pragma unroll
  for (int off = 32; off; off >>= 1) ss += __shfl_xor(ss, off, 64);
  const float rs = rsqrtf(ss * (1.f/ND) + 1e-5f);
  const float4 gv = *(const float4*)(g + lane*4);
  const float4 bv = *(const float4*)(be + lane*4);
  ushort4 o;
  o.x = f2bf(d.x*rs*gv.x + bv.x);
  o.y = f2bf(d.y*rs*gv.y + bv.y);
  o.z = f2bf(d.z*rs*gv.z + bv.z);
  o.w = f2bf(d.w*rs*gv.w + bv.w);
  *(ushort4*)(out + base) = o;
}

// ---------------- LN2: out = LN(xb + t2) -> f32 (t2 has b2 folded) -----------
__global__ __launch_bounds__(256) void ln_final_kernel(const unsigned short* __restrict__ xbp,
    const float* __restrict__ t2, const float* __restrict__ g,
    const float* __restrict__ be, float* __restrict__ out){
  const int row = blockIdx.x*4 + (threadIdx.x >> 6);
  const int lane = threadIdx.x & 63;
  const size_t base = (size_t)row*ND + lane*4;
  const ushort4 xv = *(const ushort4*)(xbp + base);
  const float4 v1 = *(const float4*)(t2 + base);
  float4 y = { bf2f(xv.x)+v1.x, bf2f(xv.y)+v1.y, bf2f(xv.z)+v1.z, bf2f(xv.w)+v1.w };
  float sum = y.x + y.y + y.z + y.w;
  #pragma unroll
  for (int off = 32; off; off >>= 1) sum += __shfl_xor(sum, off, 64);
  const float mu = sum * (1.f/ND);
  float4 d = { y.x-mu, y.y-mu, y.z-mu, y.w-mu };
  float ss = d.x*d.x + d.y*d.y + d.z*d.z + d.w*d.w;
  #pragma unroll
  for (int off = 32; off; off >>= 1) ss += __shfl_xor(ss, off, 64);
  const float rs = rsqrtf(ss * (1.f/ND) + 1e-5f);
  const float4 gv = *(const float4*)(g + lane*4);
  const float4 bv = *(const float4*)(be + lane*4);
  float4 o = { d.x*rs*gv.x + bv.x, d.y*rs*gv.y + bv.y, d.z*rs*gv.z + bv.z, d.w*rs*gv.w + bv.w };
  *(float4*)(out + base) = o;
}

// ---------------- launch ----------------
extern "C" void kernel_launch(void* const* d_in, const int* in_sizes, int n_in,
                              void* d_out, int out_size, void* d_ws, size_t ws_size,
                              hipStream_t stream){
  const float* node  = (const float*)d_in[0];
  const float* neigh = (const float*)d_in[1];
  const int*   maskp = (const int*)d_in[2];
  const float* Wq = (const float*)d_in[3];  const float* bq = (const float*)d_in[4];
  const float* Wk = (const float*)d_in[5];  /* bk dropped: softmax-invariant */
  const float* Wv = (const float*)d_in[7];  const float* bvp = (const float*)d_in[8];
  const float* Wo = (const float*)d_in[9];  const float* bo = (const float*)d_in[10];
  const float* g1 = (const float*)d_in[11]; const float* be1 = (const float*)d_in[12];
  const float* W1 = (const float*)d_in[13]; const float* b1 = (const float*)d_in[14];
  const float* W2 = (const float*)d_in[15]; const float* b2 = (const float*)d_in[16];
  const float* g2 = (const float*)d_in[17]; const float* be2 = (const float*)d_in[18];

  char* ws = (char*)d_ws;
  unsigned short* wq_b  = (unsigned short*)(ws);              // 128K
  unsigned short* w1_b  = (unsigned short*)(ws + 131072);     // 512K
  unsigned short* w2_b  = (unsigned short*)(ws + 655360);     // 512K
  unsigned short* wkt_b = (unsigned short*)(ws + 1179648);    // 128K
  unsigned short* wvo_t = (unsigned short*)(ws + 1310720);    // 1M
  float*          bvo   = (float*)(ws + 2359296);             // 1K

  const size_t MB = 1048576ull;
  char* big = ws + 4*MB;
  unsigned short* node_b = (unsigned short*)(big);            // 8M
  unsigned short* Qb     = (unsigned short*)(big + 8*MB);     // 8M
  unsigned short* xb     = (unsigned short*)(big + 16*MB);    // 8M
  unsigned short* qk     = (unsigned short*)(big + 24*MB);    // 64M
  unsigned short* pbar   = (unsigned short*)(big + 88*MB);    // 64M
  float*          t1     = (float*)(big + 152*MB);            // 16M
  unsigned short* hbuf   = (unsigned short*)(big + 168*MB);   // 32M
  float*          t2     = (float*)(big + 200*MB);            // 16M
  const size_t need = 4*MB + 216*MB;
  if (ws_size < need) return;

  // 1. all prep in one dispatch
  prep_kernel<<<6785, 256, 0, stream>>>(node, node_b, Wq, wq_b, W1, w1_b, W2, w2_b,
      Wk, wkt_b, Wv, Wo, wvo_t, bvp, bo, bvo);
  // 2. Qb = bf16((node @ Wq^T + bq) / sqrt(32))
  gemm64<1><<<dim3(NROWS/64, 2), 256, 0, stream>>>(node_b, wq_b, bq, Qb,
      256, 256, 0.17677669529663687f);
  // 3. qk[n][h*256+e]
  gemm_qk<<<dim3(NROWS/128, 2, 8), 256, 0, stream>>>(Qb, wkt_b, qk);
  // 4. fused attention
  attn2_kernel<<<NROWS/4, 256, 0, stream>>>(neigh, maskp, qk, pbar);
  // 5. t1 = pbar @ Wvo + bvo -> f32
  gemm64<2><<<dim3(NROWS/64, 2), 256, 0, stream>>>(pbar, wvo_t, bvo, t1, 256, 2048, 1.f);
  // 6. xb = LN1(node + t1)
  ln_ff_kernel<<<NROWS/4, 256, 0, stream>>>(node, t1, g1, be1, xb);
  // 7. h = relu(xb @ W1^T + b1)
  gemm64<0><<<dim3(NROWS/64, 8), 256, 0, stream>>>(xb, w1_b, b1, hbuf, 1024, 256, 1.f);
  // 8. t2 = h @ W2^T + b2 -> f32
  gemm64<2><<<dim3(NROWS/64, 2), 256, 0, stream>>>(hbuf, w2_b, b2, t2, 256, 1024, 1.f);
  // 9. out = LN2(xb + t2)
  ln_final_kernel<<<NROWS/4, 256, 0, stream>>>(xb, t2, g2, be2, (float*)d_out);
}